// Round 1
// baseline (933.921 us; speedup 1.0000x reference)
//
#include <hip/hip_runtime.h>
#include <hip/hip_bf16.h>

#define B_ 8
#define L_ 256
#define T_ 2048
#define LM_ 4096
#define DFF_ 1024
#define D_ 84
#define H_ 4
#define HD_ 21
#define BL_ (B_*L_)          // 2048
#define VISF_ (L_*D_)        // 21504
#define VKS 16
#define VCHUNK (VISF_/VKS)   // 1344

// ---------------- Stage A: build src + pad bias ----------------
__global__ void k_build_src(const float* __restrict__ vf, const float* __restrict__ gB,
                            const float* __restrict__ cemb, float* __restrict__ src,
                            float* __restrict__ neg)
{
    int row = blockIdx.x * blockDim.x + threadIdx.x;
    if (row >= BL_) return;
    float v[7];
    bool allz = true;
    #pragma unroll
    for (int c = 0; c < 7; ++c) { v[c] = vf[row*7 + c]; allz = allz && (v[c] == 0.0f); }
    neg[row] = allz ? -1e9f : 0.0f;
    float* s = src + (size_t)row * D_;
    const float TWO_PI = 6.28318530717958647692f;
    #pragma unroll
    for (int d = 0; d < 5; ++d) {
        float pmin = TWO_PI * (v[0]*gB[d] + v[1]*gB[5+d] + v[2]*gB[10+d]);
        float pmax = TWO_PI * (v[3]*gB[d] + v[4]*gB[5+d] + v[5]*gB[10+d]);
        s[d]      = sinf(pmin);  s[5+d]  = cosf(pmin);
        s[10+d]   = sinf(pmax);  s[15+d] = cosf(pmax);
    }
    int cls = (int)v[6];
    const float4* ce = reinterpret_cast<const float4*>(cemb + (size_t)cls*64);
    float4* so = reinterpret_cast<float4*>(s + 20);
    #pragma unroll
    for (int i = 0; i < 16; ++i) so[i] = ce[i];
}

// ---------------- Stage B: encoder kernels ----------------
// QKV projection, 8 rows per block (amortize w_in traffic)
__global__ __launch_bounds__(256) void k_qkv8(const float* __restrict__ src,
        const float* __restrict__ w_in, const float* __restrict__ b_in,
        float* __restrict__ qkv, int lay)
{
    __shared__ float s8[8][D_];
    int r0 = blockIdx.x * 8, tid = threadIdx.x;
    for (int idx = tid; idx < 8*D_; idx += 256) {
        int r = idx / D_, d = idx - r*D_;
        s8[r][d] = src[(size_t)(r0+r)*D_ + d];
    }
    __syncthreads();
    if (tid < 3*D_) {
        const float* w = w_in + (size_t)lay*D_*3*D_ + tid;
        float acc[8] = {};
        for (int d = 0; d < D_; ++d) {
            float wv = w[(size_t)d*3*D_];
            #pragma unroll
            for (int r = 0; r < 8; ++r) acc[r] = fmaf(s8[r][d], wv, acc[r]);
        }
        float bv = b_in[lay*3*D_ + tid];
        #pragma unroll
        for (int r = 0; r < 8; ++r) qkv[(size_t)(r0+r)*(3*D_) + tid] = acc[r] + bv;
    }
}

// attention: one block per (b,h), one thread per query row, online softmax
__global__ __launch_bounds__(256) void k_attn(const float* __restrict__ qkv,
        const float* __restrict__ neg, float* __restrict__ attn_o)
{
    __shared__ float ks[L_*HD_], vs[L_*HD_], ns[L_];
    int b = blockIdx.x >> 2, h = blockIdx.x & 3;
    int tid = threadIdx.x;
    for (int idx = tid; idx < L_*HD_; idx += 256) {
        int l = idx / HD_, d = idx - l*HD_;
        size_t base = ((size_t)(b*L_ + l))*(3*D_) + h*HD_ + d;
        ks[idx] = qkv[base + D_];
        vs[idx] = qkv[base + 2*D_];
    }
    if (tid < L_) ns[tid] = neg[b*L_ + tid];
    __syncthreads();
    float q[HD_];
    {
        size_t base = ((size_t)(b*L_ + tid))*(3*D_) + h*HD_;
        #pragma unroll
        for (int d = 0; d < HD_; ++d) q[d] = qkv[base + d];
    }
    const float scale = 0.21821789023599239f;  // 1/sqrt(21)
    float m_run = -INFINITY, l_run = 0.0f;
    float o[HD_];
    #pragma unroll
    for (int d = 0; d < HD_; ++d) o[d] = 0.0f;
    for (int m = 0; m < L_; ++m) {
        const float* krow = &ks[m*HD_];
        float sdot = 0.0f;
        #pragma unroll
        for (int d = 0; d < HD_; ++d) sdot = fmaf(q[d], krow[d], sdot);
        float sc = sdot * scale + ns[m];
        float nm = fmaxf(m_run, sc);
        float c = __expf(m_run - nm);
        float p = __expf(sc - nm);
        l_run = l_run * c + p;
        const float* vrow = &vs[m*HD_];
        #pragma unroll
        for (int d = 0; d < HD_; ++d) o[d] = fmaf(p, vrow[d], o[d]*c);
        m_run = nm;
    }
    float inv = 1.0f / l_run;
    float* op = attn_o + ((size_t)(b*L_ + tid))*D_ + h*HD_;
    #pragma unroll
    for (int d = 0; d < HD_; ++d) op[d] = o[d]*inv;
}

// out-proj + residual + LayerNorm (one row per block)
__global__ __launch_bounds__(128) void k_oproj_ln(const float* __restrict__ attn_o,
        const float* __restrict__ w_out, const float* __restrict__ b_out,
        const float* __restrict__ ln_s, const float* __restrict__ ln_b,
        float* __restrict__ src, int lay)
{
    __shared__ float os[D_];
    __shared__ float r1[128], r2[128];
    int row = blockIdx.x, tid = threadIdx.x;
    if (tid < D_) os[tid] = attn_o[(size_t)row*D_ + tid];
    __syncthreads();
    float y = 0.0f;
    if (tid < D_) {
        const float* w = w_out + (size_t)lay*D_*D_ + tid;
        float acc = b_out[lay*D_ + tid];
        for (int d = 0; d < D_; ++d) acc = fmaf(os[d], w[(size_t)d*D_], acc);
        y = src[(size_t)row*D_ + tid] + acc;
    }
    r1[tid] = (tid < D_) ? y : 0.0f;
    r2[tid] = (tid < D_) ? y*y : 0.0f;
    __syncthreads();
    for (int s = 64; s > 0; s >>= 1) {
        if (tid < s) { r1[tid] += r1[tid+s]; r2[tid] += r2[tid+s]; }
        __syncthreads();
    }
    float mean = r1[0] * (1.0f/D_);
    float var  = r2[0] * (1.0f/D_) - mean*mean;
    float rstd = rsqrtf(var + 1e-5f);
    if (tid < D_)
        src[(size_t)row*D_ + tid] = (y - mean)*rstd*ln_s[lay*D_+tid] + ln_b[lay*D_+tid];
}

// ff1: 8 rows per block, 4 output cols per thread
__global__ __launch_bounds__(256) void k_ff1(const float* __restrict__ src,
        const float* __restrict__ w_ff1, const float* __restrict__ b_ff1,
        float* __restrict__ hbuf, int lay)
{
    __shared__ float s8[8][D_];
    int r0 = blockIdx.x * 8, tid = threadIdx.x;
    for (int idx = tid; idx < 8*D_; idx += 256) {
        int r = idx / D_, d = idx - r*D_;
        s8[r][d] = src[(size_t)(r0+r)*D_ + d];
    }
    __syncthreads();
    float acc[8][4] = {};
    const float* w = w_ff1 + (size_t)lay*D_*DFF_;
    for (int d = 0; d < D_; ++d) {
        float wv[4];
        #pragma unroll
        for (int j = 0; j < 4; ++j) wv[j] = w[(size_t)d*DFF_ + tid + 256*j];
        #pragma unroll
        for (int r = 0; r < 8; ++r) {
            float sv = s8[r][d];
            #pragma unroll
            for (int j = 0; j < 4; ++j) acc[r][j] = fmaf(sv, wv[j], acc[r][j]);
        }
    }
    #pragma unroll
    for (int j = 0; j < 4; ++j) {
        float bv = b_ff1[lay*DFF_ + tid + 256*j];
        #pragma unroll
        for (int r = 0; r < 8; ++r)
            hbuf[(size_t)(r0+r)*DFF_ + tid + 256*j] = fmaxf(acc[r][j] + bv, 0.0f);
    }
}

// ff2 + residual + LN: 8 rows per block
__global__ __launch_bounds__(128) void k_ff2_ln(const float* __restrict__ hbuf,
        const float* __restrict__ w_ff2, const float* __restrict__ b_ff2,
        const float* __restrict__ ln_s, const float* __restrict__ ln_b,
        float* __restrict__ src, int lay)
{
    __shared__ __align__(16) float h8[8][DFF_];   // 32 KB
    __shared__ float r1[8][128], r2[8][128];
    int r0 = blockIdx.x * 8, tid = threadIdx.x;
    {
        const float4* hin = reinterpret_cast<const float4*>(hbuf + (size_t)r0*DFF_);
        float4* hs = reinterpret_cast<float4*>(&h8[0][0]);
        for (int idx = tid; idx < 8*DFF_/4; idx += 128) hs[idx] = hin[idx];
    }
    __syncthreads();
    float acc[8] = {};
    if (tid < D_) {
        const float* w = w_ff2 + (size_t)lay*DFF_*D_ + tid;
        for (int k = 0; k < DFF_; k += 4) {
            float wv[4];
            #pragma unroll
            for (int i = 0; i < 4; ++i) wv[i] = w[(size_t)(k+i)*D_];
            #pragma unroll
            for (int r = 0; r < 8; ++r) {
                float4 hv = *reinterpret_cast<const float4*>(&h8[r][k]);
                acc[r] += hv.x*wv[0] + hv.y*wv[1] + hv.z*wv[2] + hv.w*wv[3];
            }
        }
    }
    float y[8];
    float bv = (tid < D_) ? b_ff2[lay*D_ + tid] : 0.0f;
    #pragma unroll
    for (int r = 0; r < 8; ++r) {
        y[r] = (tid < D_) ? (src[(size_t)(r0+r)*D_ + tid] + acc[r] + bv) : 0.0f;
        r1[r][tid] = y[r];
        r2[r][tid] = y[r]*y[r];
    }
    __syncthreads();
    for (int s = 64; s > 0; s >>= 1) {
        if (tid < s) {
            #pragma unroll
            for (int r = 0; r < 8; ++r) { r1[r][tid] += r1[r][tid+s]; r2[r][tid] += r2[r][tid+s]; }
        }
        __syncthreads();
    }
    if (tid < D_) {
        #pragma unroll
        for (int r = 0; r < 8; ++r) {
            float mean = r1[r][0] * (1.0f/D_);
            float var  = r2[r][0] * (1.0f/D_) - mean*mean;
            float rstd = rsqrtf(var + 1e-5f);
            src[(size_t)(r0+r)*D_ + tid] = (y[r]-mean)*rstd*ln_s[lay*D_+tid] + ln_b[lay*D_+tid];
        }
    }
}

// ---------------- Stage C: head ----------------
// vis_part split-K partials: grid (8 n-tiles, 16 k-splits)
__global__ __launch_bounds__(256) void k_vis_gemm(const float* __restrict__ src,
        const float* __restrict__ w0, float* __restrict__ partials)
{
    __shared__ float vf[8*VCHUNK];   // 43 KB
    int nt = blockIdx.x, sp = blockIdx.y, tid = threadIdx.x;
    int k0 = sp * VCHUNK;
    for (int idx = tid; idx < 8*VCHUNK; idx += 256) {
        int r = idx / VCHUNK, c = idx - r*VCHUNK;
        vf[idx] = src[(size_t)r*VISF_ + k0 + c];
    }
    __syncthreads();
    int n = nt*128 + (tid & 127);
    int kh = tid >> 7;
    float acc[8] = {};
    const float* wp = w0 + (size_t)(k0 + kh*(VCHUNK/2))*DFF_ + n;
    const float* vp = vf + kh*(VCHUNK/2);
    for (int kk = 0; kk < VCHUNK/2; ++kk) {
        float w = wp[(size_t)kk*DFF_];
        #pragma unroll
        for (int m = 0; m < 8; ++m) acc[m] = fmaf(vp[m*VCHUNK + kk], w, acc[m]);
    }
    __syncthreads();
    float* red = vf;  // reuse LDS
    #pragma unroll
    for (int m = 0; m < 8; ++m) red[m*256 + tid] = acc[m];
    __syncthreads();
    if (kh == 0) {
        #pragma unroll
        for (int m = 0; m < 8; ++m)
            partials[(size_t)sp*(8*DFF_) + m*DFF_ + n] = red[m*256 + tid] + red[m*256 + tid + 128];
    }
}

__global__ void k_vis_reduce(const float* __restrict__ partials, float* __restrict__ vis)
{
    int o = blockIdx.x*256 + threadIdx.x;   // < 8192
    float s = 0.0f;
    for (int sp = 0; sp < VKS; ++sp) s += partials[(size_t)sp*8192 + o];
    vis[o] = s;
}

// fp32 tiled GEMM: C[M,N] = act(A[M,K] @ W[K,N] + bias (+ vis[bidx[m]]))
// BM=64, BN=128, BK=32, 256 threads, 4x8 per thread. M%64==0, N%128==0, K%32==0.
template<bool RELU, bool ADD_VIS>
__global__ __launch_bounds__(256) void gemm_k(
        const float* __restrict__ A, const float* __restrict__ W,
        const float* __restrict__ bias, const float* __restrict__ vis,
        const int* __restrict__ bidx, float* __restrict__ C,
        int M, int N, int K)
{
    __shared__ __align__(16) float As[32][64];    // [k][m]
    __shared__ __align__(16) float Bs[32][128];   // [k][n]
    int tid = threadIdx.x;
    int bm = blockIdx.x * 64;
    int bn = blockIdx.y * 128;
    int ty = tid >> 4, tx = tid & 15;
    float acc[4][8] = {};
    for (int k0 = 0; k0 < K; k0 += 32) {
        #pragma unroll
        for (int i = 0; i < 2; ++i) {
            int idx = tid + i*256;
            int r = idx >> 3, q = idx & 7;
            float4 a = *reinterpret_cast<const float4*>(&A[(size_t)(bm + r)*K + k0 + q*4]);
            As[q*4+0][r] = a.x; As[q*4+1][r] = a.y; As[q*4+2][r] = a.z; As[q*4+3][r] = a.w;
        }
        #pragma unroll
        for (int i = 0; i < 4; ++i) {
            int idx = tid + i*256;
            int r = idx >> 5, c4 = idx & 31;
            *reinterpret_cast<float4*>(&Bs[r][c4*4]) =
                *reinterpret_cast<const float4*>(&W[(size_t)(k0 + r)*N + bn + c4*4]);
        }
        __syncthreads();
        #pragma unroll
        for (int kk = 0; kk < 32; ++kk) {
            float4 a4  = *reinterpret_cast<const float4*>(&As[kk][ty*4]);
            float4 b4a = *reinterpret_cast<const float4*>(&Bs[kk][tx*8]);
            float4 b4b = *reinterpret_cast<const float4*>(&Bs[kk][tx*8+4]);
            float av[4] = {a4.x, a4.y, a4.z, a4.w};
            float bv[8] = {b4a.x, b4a.y, b4a.z, b4a.w, b4b.x, b4b.y, b4b.z, b4b.w};
            #pragma unroll
            for (int i = 0; i < 4; ++i)
                #pragma unroll
                for (int j = 0; j < 8; ++j)
                    acc[i][j] = fmaf(av[i], bv[j], acc[i][j]);
        }
        __syncthreads();
    }
    #pragma unroll
    for (int i = 0; i < 4; ++i) {
        int row = bm + ty*4 + i;
        const float* vrow = nullptr;
        if (ADD_VIS) vrow = vis + (size_t)bidx[row]*DFF_ + bn;
        float ov[8];
        #pragma unroll
        for (int j = 0; j < 8; ++j) {
            float v = acc[i][j] + bias[bn + tx*8 + j];
            if (ADD_VIS) v += vrow[tx*8 + j];
            if (RELU) v = fmaxf(v, 0.0f);
            ov[j] = v;
        }
        float4* cp = reinterpret_cast<float4*>(&C[(size_t)row*N + bn + tx*8]);
        cp[0] = make_float4(ov[0], ov[1], ov[2], ov[3]);
        cp[1] = make_float4(ov[4], ov[5], ov[6], ov[7]);
    }
}

// final 1024 -> 6
__global__ __launch_bounds__(64) void k_final(const float* __restrict__ h,
        const float* __restrict__ w4, const float* __restrict__ b4, float* __restrict__ out)
{
    int t = blockIdx.x, lane = threadIdx.x;
    float acc[6] = {};
    for (int k = lane; k < DFF_; k += 64) {
        float hv = h[(size_t)t*DFF_ + k];
        #pragma unroll
        for (int j = 0; j < 6; ++j) acc[j] = fmaf(hv, w4[k*6 + j], acc[j]);
    }
    #pragma unroll
    for (int j = 0; j < 6; ++j)
        #pragma unroll
        for (int s = 32; s > 0; s >>= 1) acc[j] += __shfl_down(acc[j], s);
    if (lane == 0) {
        #pragma unroll
        for (int j = 0; j < 6; ++j) out[(size_t)t*6 + j] = acc[j] + b4[j];
    }
}

extern "C" void kernel_launch(void* const* d_in, const int* in_sizes, int n_in,
                              void* d_out, int out_size, void* d_ws, size_t ws_size,
                              hipStream_t stream)
{
    const float* grd   = (const float*)d_in[0];
    const float* vfeat = (const float*)d_in[1];
    const int*   tbi   = (const int*)  d_in[2];
    const float* gB    = (const float*)d_in[3];
    const float* cemb  = (const float*)d_in[4];
    const float* w_in  = (const float*)d_in[5];
    const float* b_in  = (const float*)d_in[6];
    const float* w_out = (const float*)d_in[7];
    const float* b_out = (const float*)d_in[8];
    const float* ln1_s = (const float*)d_in[9];
    const float* ln1_b = (const float*)d_in[10];
    const float* w_ff1 = (const float*)d_in[11];
    const float* b_ff1 = (const float*)d_in[12];
    const float* w_ff2 = (const float*)d_in[13];
    const float* b_ff2 = (const float*)d_in[14];
    const float* ln2_s = (const float*)d_in[15];
    const float* ln2_b = (const float*)d_in[16];
    const float* w0    = (const float*)d_in[17];
    const float* b0    = (const float*)d_in[18];
    const float* w1    = (const float*)d_in[19];
    const float* b1    = (const float*)d_in[20];
    const float* w2    = (const float*)d_in[21];
    const float* b2    = (const float*)d_in[22];
    const float* w3    = (const float*)d_in[23];
    const float* b3    = (const float*)d_in[24];
    const float* w4    = (const float*)d_in[25];
    const float* b4    = (const float*)d_in[26];

    float* ws = (float*)d_ws;
    float* src    = ws;                       // 172032
    float* neg    = src    + 172032;          // 2048
    float* qkv    = neg    + 2048;            // 516096
    float* attn_o = qkv    + 516096;          // 172032
    float* hbuf   = attn_o + 172032;          // 2097152
    float* parts  = hbuf   + 2097152;         // 131072
    float* visp   = parts  + 131072;          // 8192
    float* ha     = visp   + 8192;            // 2097152
    float* hb     = ha     + 2097152;         // 2097152  (total ~29.2 MB)

    k_build_src<<<8, 256, 0, stream>>>(vfeat, gB, cemb, src, neg);

    for (int lay = 0; lay < 2; ++lay) {
        k_qkv8    <<<BL_/8, 256, 0, stream>>>(src, w_in, b_in, qkv, lay);
        k_attn    <<<B_*H_, 256, 0, stream>>>(qkv, neg, attn_o);
        k_oproj_ln<<<BL_,   128, 0, stream>>>(attn_o, w_out, b_out, ln1_s, ln1_b, src, lay);
        k_ff1     <<<BL_/8, 256, 0, stream>>>(src, w_ff1, b_ff1, hbuf, lay);
        k_ff2_ln  <<<BL_/8, 128, 0, stream>>>(hbuf, w_ff2, b_ff2, ln2_s, ln2_b, src, lay);
    }

    k_vis_gemm  <<<dim3(8, VKS), 256, 0, stream>>>(src, w0, parts);
    k_vis_reduce<<<32, 256, 0, stream>>>(parts, visp);

    dim3 ggrid(T_/64, DFF_/128);
    gemm_k<true,  true ><<<ggrid, 256, 0, stream>>>(grd, w0 + (size_t)VISF_*DFF_, b0, visp, tbi, ha, T_, DFF_, LM_);
    gemm_k<true,  false><<<ggrid, 256, 0, stream>>>(ha, w1, b1, nullptr, nullptr, hb, T_, DFF_, DFF_);
    gemm_k<true,  false><<<ggrid, 256, 0, stream>>>(hb, w2, b2, nullptr, nullptr, ha, T_, DFF_, DFF_);
    gemm_k<true,  false><<<ggrid, 256, 0, stream>>>(ha, w3, b3, nullptr, nullptr, hb, T_, DFF_, DFF_);

    k_final<<<T_, 64, 0, stream>>>(hb, w4, b4, (float*)d_out);
}

// Round 2
// 556.823 us; speedup vs baseline: 1.6772x; 1.6772x over previous
//
#include <hip/hip_runtime.h>
#include <hip/hip_bf16.h>

#define B_ 8
#define L_ 256
#define T_ 2048
#define LM_ 4096
#define DFF_ 1024
#define D_ 84
#define H_ 4
#define HD_ 21
#define BL_ (B_*L_)          // 2048
#define VISF_ (L_*D_)        // 21504
#define VKS 16
#define VCHUNK (VISF_/VKS)   // 1344

typedef __attribute__((ext_vector_type(8))) short bf16x8;
typedef __attribute__((ext_vector_type(4))) float f32x4;

typedef const __attribute__((address_space(1))) int* gas_p;
typedef __attribute__((address_space(3))) int* las_p;
__device__ __forceinline__ void gld_lds16(const void* g, void* l) {
    __builtin_amdgcn_global_load_lds((gas_p)g, (las_p)l, 16, 0, 0);
}

// ---------------- Stage A: build src + pad bias ----------------
__global__ void k_build_src(const float* __restrict__ vf, const float* __restrict__ gB,
                            const float* __restrict__ cemb, float* __restrict__ src,
                            float* __restrict__ neg)
{
    int row = blockIdx.x * blockDim.x + threadIdx.x;
    if (row >= BL_) return;
    float v[7];
    bool allz = true;
    #pragma unroll
    for (int c = 0; c < 7; ++c) { v[c] = vf[row*7 + c]; allz = allz && (v[c] == 0.0f); }
    neg[row] = allz ? -1e9f : 0.0f;
    float* s = src + (size_t)row * D_;
    const float TWO_PI = 6.28318530717958647692f;
    #pragma unroll
    for (int d = 0; d < 5; ++d) {
        float pmin = TWO_PI * (v[0]*gB[d] + v[1]*gB[5+d] + v[2]*gB[10+d]);
        float pmax = TWO_PI * (v[3]*gB[d] + v[4]*gB[5+d] + v[5]*gB[10+d]);
        s[d]      = sinf(pmin);  s[5+d]  = cosf(pmin);
        s[10+d]   = sinf(pmax);  s[15+d] = cosf(pmax);
    }
    int cls = (int)v[6];
    const float4* ce = reinterpret_cast<const float4*>(cemb + (size_t)cls*64);
    float4* so = reinterpret_cast<float4*>(s + 20);
    #pragma unroll
    for (int i = 0; i < 16; ++i) so[i] = ce[i];
}

// ---------------- Stage B: encoder kernels (unchanged this round) ----------------
__global__ __launch_bounds__(256) void k_qkv8(const float* __restrict__ src,
        const float* __restrict__ w_in, const float* __restrict__ b_in,
        float* __restrict__ qkv, int lay)
{
    __shared__ float s8[8][D_];
    int r0 = blockIdx.x * 8, tid = threadIdx.x;
    for (int idx = tid; idx < 8*D_; idx += 256) {
        int r = idx / D_, d = idx - r*D_;
        s8[r][d] = src[(size_t)(r0+r)*D_ + d];
    }
    __syncthreads();
    if (tid < 3*D_) {
        const float* w = w_in + (size_t)lay*D_*3*D_ + tid;
        float acc[8] = {};
        for (int d = 0; d < D_; ++d) {
            float wv = w[(size_t)d*3*D_];
            #pragma unroll
            for (int r = 0; r < 8; ++r) acc[r] = fmaf(s8[r][d], wv, acc[r]);
        }
        float bv = b_in[lay*3*D_ + tid];
        #pragma unroll
        for (int r = 0; r < 8; ++r) qkv[(size_t)(r0+r)*(3*D_) + tid] = acc[r] + bv;
    }
}

__global__ __launch_bounds__(256) void k_attn(const float* __restrict__ qkv,
        const float* __restrict__ neg, float* __restrict__ attn_o)
{
    __shared__ float ks[L_*HD_], vs[L_*HD_], ns[L_];
    int b = blockIdx.x >> 2, h = blockIdx.x & 3;
    int tid = threadIdx.x;
    for (int idx = tid; idx < L_*HD_; idx += 256) {
        int l = idx / HD_, d = idx - l*HD_;
        size_t base = ((size_t)(b*L_ + l))*(3*D_) + h*HD_ + d;
        ks[idx] = qkv[base + D_];
        vs[idx] = qkv[base + 2*D_];
    }
    if (tid < L_) ns[tid] = neg[b*L_ + tid];
    __syncthreads();
    float q[HD_];
    {
        size_t base = ((size_t)(b*L_ + tid))*(3*D_) + h*HD_;
        #pragma unroll
        for (int d = 0; d < HD_; ++d) q[d] = qkv[base + d];
    }
    const float scale = 0.21821789023599239f;  // 1/sqrt(21)
    float m_run = -INFINITY, l_run = 0.0f;
    float o[HD_];
    #pragma unroll
    for (int d = 0; d < HD_; ++d) o[d] = 0.0f;
    for (int m = 0; m < L_; ++m) {
        const float* krow = &ks[m*HD_];
        float sdot = 0.0f;
        #pragma unroll
        for (int d = 0; d < HD_; ++d) sdot = fmaf(q[d], krow[d], sdot);
        float sc = sdot * scale + ns[m];
        float nm = fmaxf(m_run, sc);
        float c = __expf(m_run - nm);
        float p = __expf(sc - nm);
        l_run = l_run * c + p;
        const float* vrow = &vs[m*HD_];
        #pragma unroll
        for (int d = 0; d < HD_; ++d) o[d] = fmaf(p, vrow[d], o[d]*c);
        m_run = nm;
    }
    float inv = 1.0f / l_run;
    float* op = attn_o + ((size_t)(b*L_ + tid))*D_ + h*HD_;
    #pragma unroll
    for (int d = 0; d < HD_; ++d) op[d] = o[d]*inv;
}

__global__ __launch_bounds__(128) void k_oproj_ln(const float* __restrict__ attn_o,
        const float* __restrict__ w_out, const float* __restrict__ b_out,
        const float* __restrict__ ln_s, const float* __restrict__ ln_b,
        float* __restrict__ src, int lay)
{
    __shared__ float os[D_];
    __shared__ float r1[128], r2[128];
    int row = blockIdx.x, tid = threadIdx.x;
    if (tid < D_) os[tid] = attn_o[(size_t)row*D_ + tid];
    __syncthreads();
    float y = 0.0f;
    if (tid < D_) {
        const float* w = w_out + (size_t)lay*D_*D_ + tid;
        float acc = b_out[lay*D_ + tid];
        for (int d = 0; d < D_; ++d) acc = fmaf(os[d], w[(size_t)d*D_], acc);
        y = src[(size_t)row*D_ + tid] + acc;
    }
    r1[tid] = (tid < D_) ? y : 0.0f;
    r2[tid] = (tid < D_) ? y*y : 0.0f;
    __syncthreads();
    for (int s = 64; s > 0; s >>= 1) {
        if (tid < s) { r1[tid] += r1[tid+s]; r2[tid] += r2[tid+s]; }
        __syncthreads();
    }
    float mean = r1[0] * (1.0f/D_);
    float var  = r2[0] * (1.0f/D_) - mean*mean;
    float rstd = rsqrtf(var + 1e-5f);
    if (tid < D_)
        src[(size_t)row*D_ + tid] = (y - mean)*rstd*ln_s[lay*D_+tid] + ln_b[lay*D_+tid];
}

__global__ __launch_bounds__(256) void k_ff1(const float* __restrict__ src,
        const float* __restrict__ w_ff1, const float* __restrict__ b_ff1,
        float* __restrict__ hbuf, int lay)
{
    __shared__ float s8[8][D_];
    int r0 = blockIdx.x * 8, tid = threadIdx.x;
    for (int idx = tid; idx < 8*D_; idx += 256) {
        int r = idx / D_, d = idx - r*D_;
        s8[r][d] = src[(size_t)(r0+r)*D_ + d];
    }
    __syncthreads();
    float acc[8][4] = {};
    const float* w = w_ff1 + (size_t)lay*D_*DFF_;
    for (int d = 0; d < D_; ++d) {
        float wv[4];
        #pragma unroll
        for (int j = 0; j < 4; ++j) wv[j] = w[(size_t)d*DFF_ + tid + 256*j];
        #pragma unroll
        for (int r = 0; r < 8; ++r) {
            float sv = s8[r][d];
            #pragma unroll
            for (int j = 0; j < 4; ++j) acc[r][j] = fmaf(sv, wv[j], acc[r][j]);
        }
    }
    #pragma unroll
    for (int j = 0; j < 4; ++j) {
        float bv = b_ff1[lay*DFF_ + tid + 256*j];
        #pragma unroll
        for (int r = 0; r < 8; ++r)
            hbuf[(size_t)(r0+r)*DFF_ + tid + 256*j] = fmaxf(acc[r][j] + bv, 0.0f);
    }
}

__global__ __launch_bounds__(128) void k_ff2_ln(const float* __restrict__ hbuf,
        const float* __restrict__ w_ff2, const float* __restrict__ b_ff2,
        const float* __restrict__ ln_s, const float* __restrict__ ln_b,
        float* __restrict__ src, int lay)
{
    __shared__ __align__(16) float h8[8][DFF_];   // 32 KB
    __shared__ float r1[8][128], r2[8][128];
    int r0 = blockIdx.x * 8, tid = threadIdx.x;
    {
        const float4* hin = reinterpret_cast<const float4*>(hbuf + (size_t)r0*DFF_);
        float4* hs = reinterpret_cast<float4*>(&h8[0][0]);
        for (int idx = tid; idx < 8*DFF_/4; idx += 128) hs[idx] = hin[idx];
    }
    __syncthreads();
    float acc[8] = {};
    if (tid < D_) {
        const float* w = w_ff2 + (size_t)lay*DFF_*D_ + tid;
        for (int k = 0; k < DFF_; k += 4) {
            float wv[4];
            #pragma unroll
            for (int i = 0; i < 4; ++i) wv[i] = w[(size_t)(k+i)*D_];
            #pragma unroll
            for (int r = 0; r < 8; ++r) {
                float4 hv = *reinterpret_cast<const float4*>(&h8[r][k]);
                acc[r] += hv.x*wv[0] + hv.y*wv[1] + hv.z*wv[2] + hv.w*wv[3];
            }
        }
    }
    float y[8];
    float bv = (tid < D_) ? b_ff2[lay*D_ + tid] : 0.0f;
    #pragma unroll
    for (int r = 0; r < 8; ++r) {
        y[r] = (tid < D_) ? (src[(size_t)(r0+r)*D_ + tid] + acc[r] + bv) : 0.0f;
        r1[r][tid] = y[r];
        r2[r][tid] = y[r]*y[r];
    }
    __syncthreads();
    for (int s = 64; s > 0; s >>= 1) {
        if (tid < s) {
            #pragma unroll
            for (int r = 0; r < 8; ++r) { r1[r][tid] += r1[r][tid+s]; r2[r][tid] += r2[r][tid+s]; }
        }
        __syncthreads();
    }
    if (tid < D_) {
        #pragma unroll
        for (int r = 0; r < 8; ++r) {
            float mean = r1[r][0] * (1.0f/D_);
            float var  = r2[r][0] * (1.0f/D_) - mean*mean;
            float rstd = rsqrtf(var + 1e-5f);
            src[(size_t)(r0+r)*D_ + tid] = (y[r]-mean)*rstd*ln_s[lay*D_+tid] + ln_b[lay*D_+tid];
        }
    }
}

// ---------------- vis part (fp32, exact): 8 rows x w0_top ----------------
__global__ __launch_bounds__(256) void k_vis_gemm(const float* __restrict__ src,
        const float* __restrict__ w0, float* __restrict__ partials)
{
    __shared__ float vf[8*VCHUNK];   // 43 KB
    int nt = blockIdx.x, sp = blockIdx.y, tid = threadIdx.x;
    int k0 = sp * VCHUNK;
    for (int idx = tid; idx < 8*VCHUNK; idx += 256) {
        int r = idx / VCHUNK, c = idx - r*VCHUNK;
        vf[idx] = src[(size_t)r*VISF_ + k0 + c];
    }
    __syncthreads();
    int n = nt*128 + (tid & 127);
    int kh = tid >> 7;
    float acc[8] = {};
    const float* wp = w0 + (size_t)(k0 + kh*(VCHUNK/2))*DFF_ + n;
    const float* vp = vf + kh*(VCHUNK/2);
    for (int kk = 0; kk < VCHUNK/2; ++kk) {
        float w = wp[(size_t)kk*DFF_];
        #pragma unroll
        for (int m = 0; m < 8; ++m) acc[m] = fmaf(vp[m*VCHUNK + kk], w, acc[m]);
    }
    __syncthreads();
    float* red = vf;  // reuse LDS
    #pragma unroll
    for (int m = 0; m < 8; ++m) red[m*256 + tid] = acc[m];
    __syncthreads();
    if (kh == 0) {
        #pragma unroll
        for (int m = 0; m < 8; ++m)
            partials[(size_t)sp*(8*DFF_) + m*DFF_ + n] = red[m*256 + tid] + red[m*256 + tid + 128];
    }
}

__global__ void k_vis_reduce(const float* __restrict__ partials, float* __restrict__ vis)
{
    int o = blockIdx.x*256 + threadIdx.x;   // < 8192
    float s = 0.0f;
    for (int sp = 0; sp < VKS; ++sp) s += partials[(size_t)sp*8192 + o];
    vis[o] = s;
}

// ---------------- bf16 conversion helpers ----------------
struct bh4 { __hip_bfloat16 x, y, z, w; };

__global__ __launch_bounds__(256) void k_f2b(const float* __restrict__ in,
        __hip_bfloat16* __restrict__ out, int n4)
{
    int i = blockIdx.x*256 + threadIdx.x;
    if (i >= n4) return;
    float4 v = reinterpret_cast<const float4*>(in)[i];
    bh4 o = { __float2bfloat16(v.x), __float2bfloat16(v.y),
              __float2bfloat16(v.z), __float2bfloat16(v.w) };
    reinterpret_cast<bh4*>(out)[i] = o;
}

// transpose+convert: W[K][N] fp32 -> WT[N][K] bf16
__global__ __launch_bounds__(256) void k_wT(const float* __restrict__ W,
        __hip_bfloat16* __restrict__ WT, int K, int N)
{
    __shared__ float t[32][33];
    int kb = blockIdx.x*32, nb = blockIdx.y*32;
    int tx = threadIdx.x & 31, ty = threadIdx.x >> 5;   // ty 0..7
    #pragma unroll
    for (int i = 0; i < 4; ++i)
        t[ty + i*8][tx] = W[(size_t)(kb + ty + i*8)*N + nb + tx];
    __syncthreads();
    #pragma unroll
    for (int i = 0; i < 4; ++i)
        WT[(size_t)(nb + ty + i*8)*K + kb + tx] = __float2bfloat16(t[tx][ty + i*8]);
}

// ---------------- MFMA head GEMM ----------------
// C[M=2048][N=1024] = relu(A[M][K]_bf16 @ WT[N][K]_bf16^T + bias (+ vis[bidx[m]]))
// BM=64, BN=128, BK=64, 4 waves; wave computes 32x64 (2x4 frags of 16x16).
// LDS packed [kb][m][8] / [kb][n][8]: every frag read is a conflict-free ds_read_b128.
template<bool ADD_VIS>
__global__ __launch_bounds__(256) void mfma_gemm(
        const __hip_bfloat16* __restrict__ A,   // [M][K]
        const __hip_bfloat16* __restrict__ WT,  // [N][K]
        const float* __restrict__ bias,         // [N]
        const float* __restrict__ vis,          // [8][1024]
        const int* __restrict__ bidx,           // [M]
        __hip_bfloat16* __restrict__ C,         // [M][N]
        int K)
{
    constexpr int N = 1024;
    __shared__ __align__(16) __hip_bfloat16 sA[4096];   //  8 KB
    __shared__ __align__(16) __hip_bfloat16 sB[8192];   // 16 KB
    int tid = threadIdx.x;
    int bm = blockIdx.x * 64, bn = blockIdx.y * 128;
    int wave = tid >> 6, lane = tid & 63;
    int wr = wave >> 1, wc = wave & 1;
    int l15 = lane & 15, l4 = lane >> 4;
    f32x4 acc[2][4] = {};

    for (int k0 = 0; k0 < K; k0 += 64) {
        #pragma unroll
        for (int r = 0; r < 2; ++r) {          // A tile: 64m x 64k
            int idx = tid + r*256;
            int kb = idx >> 6, m = idx & 63;
            gld_lds16(A + (size_t)(bm + m)*K + k0 + kb*8, (char*)sA + idx*16);
        }
        #pragma unroll
        for (int r = 0; r < 4; ++r) {          // B tile: 128n x 64k
            int idx = tid + r*256;
            int kb = idx >> 7, n = idx & 127;
            gld_lds16(WT + (size_t)(bn + n)*K + k0 + kb*8, (char*)sB + idx*16);
        }
        __syncthreads();
        #pragma unroll
        for (int ks = 0; ks < 2; ++ks) {
            bf16x8 af[2], bfr[4];
            #pragma unroll
            for (int mi = 0; mi < 2; ++mi)
                af[mi] = *reinterpret_cast<const bf16x8*>(
                    &sA[(size_t)((ks*4 + l4)*64 + wr*32 + mi*16 + l15) * 8]);
            #pragma unroll
            for (int ni = 0; ni < 4; ++ni)
                bfr[ni] = *reinterpret_cast<const bf16x8*>(
                    &sB[(size_t)((ks*4 + l4)*128 + wc*64 + ni*16 + l15) * 8]);
            #pragma unroll
            for (int mi = 0; mi < 2; ++mi)
                #pragma unroll
                for (int ni = 0; ni < 4; ++ni)
                    acc[mi][ni] = __builtin_amdgcn_mfma_f32_16x16x32_bf16(
                        af[mi], bfr[ni], acc[mi][ni], 0, 0, 0);
        }
        __syncthreads();
    }

    // epilogue: D[row=(lane>>4)*4+reg][col=lane&15] per frag (m89-verified)
    #pragma unroll
    for (int mi = 0; mi < 2; ++mi) {
        #pragma unroll
        for (int reg = 0; reg < 4; ++reg) {
            int row = bm + wr*32 + mi*16 + l4*4 + reg;
            const float* vrow = nullptr;
            if (ADD_VIS) vrow = vis + (size_t)bidx[row]*1024;
            #pragma unroll
            for (int ni = 0; ni < 4; ++ni) {
                int col = bn + wc*64 + ni*16 + l15;
                float v = acc[mi][ni][reg] + bias[col];
                if (ADD_VIS) v += vrow[col];
                v = fmaxf(v, 0.0f);
                C[(size_t)row*N + col] = __float2bfloat16(v);
            }
        }
    }
}

// final 1024 -> 6 (bf16 h)
__global__ __launch_bounds__(64) void k_final(const __hip_bfloat16* __restrict__ h,
        const float* __restrict__ w4, const float* __restrict__ b4, float* __restrict__ out)
{
    int t = blockIdx.x, lane = threadIdx.x;
    float acc[6] = {};
    for (int k = lane; k < DFF_; k += 64) {
        float hv = __bfloat162float(h[(size_t)t*DFF_ + k]);
        #pragma unroll
        for (int j = 0; j < 6; ++j) acc[j] = fmaf(hv, w4[k*6 + j], acc[j]);
    }
    #pragma unroll
    for (int j = 0; j < 6; ++j)
        #pragma unroll
        for (int s = 32; s > 0; s >>= 1) acc[j] += __shfl_down(acc[j], s);
    if (lane == 0) {
        #pragma unroll
        for (int j = 0; j < 6; ++j) out[(size_t)t*6 + j] = acc[j] + b4[j];
    }
}

extern "C" void kernel_launch(void* const* d_in, const int* in_sizes, int n_in,
                              void* d_out, int out_size, void* d_ws, size_t ws_size,
                              hipStream_t stream)
{
    const float* grd   = (const float*)d_in[0];
    const float* vfeat = (const float*)d_in[1];
    const int*   tbi   = (const int*)  d_in[2];
    const float* gB    = (const float*)d_in[3];
    const float* cemb  = (const float*)d_in[4];
    const float* w_in  = (const float*)d_in[5];
    const float* b_in  = (const float*)d_in[6];
    const float* w_out = (const float*)d_in[7];
    const float* b_out = (const float*)d_in[8];
    const float* ln1_s = (const float*)d_in[9];
    const float* ln1_b = (const float*)d_in[10];
    const float* w_ff1 = (const float*)d_in[11];
    const float* b_ff1 = (const float*)d_in[12];
    const float* w_ff2 = (const float*)d_in[13];
    const float* b_ff2 = (const float*)d_in[14];
    const float* ln2_s = (const float*)d_in[15];
    const float* ln2_b = (const float*)d_in[16];
    const float* w0    = (const float*)d_in[17];
    const float* b0    = (const float*)d_in[18];
    const float* w1    = (const float*)d_in[19];
    const float* b1    = (const float*)d_in[20];
    const float* w2    = (const float*)d_in[21];
    const float* b2    = (const float*)d_in[22];
    const float* w3    = (const float*)d_in[23];
    const float* b3    = (const float*)d_in[24];
    const float* w4    = (const float*)d_in[25];
    const float* b4    = (const float*)d_in[26];

    float* ws = (float*)d_ws;
    float* src    = ws;                       // 172032
    float* neg    = src    + 172032;          // 2048
    float* qkv    = neg    + 2048;            // 516096
    float* attn_o = qkv    + 516096;          // 172032
    float* hbuf   = attn_o + 172032;          // 2097152
    float* parts  = hbuf   + 2097152;         // 131072
    float* visp   = parts  + 131072;          // 8192
    float* fend   = visp   + 8192;            // fp32 region: ~12.4 MB
    __hip_bfloat16* grdb = (__hip_bfloat16*)fend;        // 8388608
    __hip_bfloat16* w0t  = grdb + 8388608;               // 4194304
    __hip_bfloat16* w1t  = w0t  + 4194304;               // 1048576
    __hip_bfloat16* w2t  = w1t  + 1048576;               // 1048576
    __hip_bfloat16* w3t  = w2t  + 1048576;               // 1048576
    __hip_bfloat16* hab  = w3t  + 1048576;               // 2097152
    __hip_bfloat16* hbb  = hab  + 2097152;               // 2097152  (total ~52.3 MB)

    // conversions (independent of encoder; issue first)
    k_f2b<<<(T_*LM_/4 + 255)/256, 256, 0, stream>>>(grd, grdb, T_*LM_/4);
    k_wT<<<dim3(LM_/32,  DFF_/32), 256, 0, stream>>>(w0 + (size_t)VISF_*DFF_, w0t, LM_,  DFF_);
    k_wT<<<dim3(DFF_/32, DFF_/32), 256, 0, stream>>>(w1, w1t, DFF_, DFF_);
    k_wT<<<dim3(DFF_/32, DFF_/32), 256, 0, stream>>>(w2, w2t, DFF_, DFF_);
    k_wT<<<dim3(DFF_/32, DFF_/32), 256, 0, stream>>>(w3, w3t, DFF_, DFF_);

    k_build_src<<<8, 256, 0, stream>>>(vfeat, gB, cemb, src, neg);

    for (int lay = 0; lay < 2; ++lay) {
        k_qkv8    <<<BL_/8, 256, 0, stream>>>(src, w_in, b_in, qkv, lay);
        k_attn    <<<B_*H_, 256, 0, stream>>>(qkv, neg, attn_o);
        k_oproj_ln<<<BL_,   128, 0, stream>>>(attn_o, w_out, b_out, ln1_s, ln1_b, src, lay);
        k_ff1     <<<BL_/8, 256, 0, stream>>>(src, w_ff1, b_ff1, hbuf, lay);
        k_ff2_ln  <<<BL_/8, 128, 0, stream>>>(hbuf, w_ff2, b_ff2, ln2_s, ln2_b, src, lay);
    }

    k_vis_gemm  <<<dim3(8, VKS), 256, 0, stream>>>(src, w0, parts);
    k_vis_reduce<<<32, 256, 0, stream>>>(parts, visp);

    dim3 mg(T_/64, DFF_/128);   // (32, 8)
    mfma_gemm<true ><<<mg, 256, 0, stream>>>(grdb, w0t, b0, visp, tbi, hab, LM_);
    mfma_gemm<false><<<mg, 256, 0, stream>>>(hab,  w1t, b1, nullptr, nullptr, hbb, DFF_);
    mfma_gemm<false><<<mg, 256, 0, stream>>>(hbb,  w2t, b2, nullptr, nullptr, hab, DFF_);
    mfma_gemm<false><<<mg, 256, 0, stream>>>(hab,  w3t, b3, nullptr, nullptr, hbb, DFF_);

    k_final<<<T_, 64, 0, stream>>>(hbb, w4, b4, (float*)d_out);
}

// Round 3
// 541.763 us; speedup vs baseline: 1.7239x; 1.0278x over previous
//
#include <hip/hip_runtime.h>
#include <hip/hip_bf16.h>

#define B_ 8
#define L_ 256
#define T_ 2048
#define LM_ 4096
#define DFF_ 1024
#define D_ 84
#define H_ 4
#define HD_ 21
#define BL_ (B_*L_)          // 2048
#define VISF_ (L_*D_)        // 21504
#define VKS 16
#define VCHUNK (VISF_/VKS)   // 1344

typedef __attribute__((ext_vector_type(8))) short bf16x8;
typedef __attribute__((ext_vector_type(4))) float f32x4;

typedef const __attribute__((address_space(1))) int* gas_p;
typedef __attribute__((address_space(3))) int* las_p;
__device__ __forceinline__ void gld_lds16(const void* g, void* l) {
    __builtin_amdgcn_global_load_lds((gas_p)g, (las_p)l, 16, 0, 0);
}

// ---------------- Stage A: build src + pad bias ----------------
__global__ void k_build_src(const float* __restrict__ vf, const float* __restrict__ gB,
                            const float* __restrict__ cemb, float* __restrict__ src,
                            float* __restrict__ neg)
{
    int row = blockIdx.x * blockDim.x + threadIdx.x;
    if (row >= BL_) return;
    float v[7];
    bool allz = true;
    #pragma unroll
    for (int c = 0; c < 7; ++c) { v[c] = vf[row*7 + c]; allz = allz && (v[c] == 0.0f); }
    neg[row] = allz ? -1e9f : 0.0f;
    float* s = src + (size_t)row * D_;
    const float TWO_PI = 6.28318530717958647692f;
    #pragma unroll
    for (int d = 0; d < 5; ++d) {
        float pmin = TWO_PI * (v[0]*gB[d] + v[1]*gB[5+d] + v[2]*gB[10+d]);
        float pmax = TWO_PI * (v[3]*gB[d] + v[4]*gB[5+d] + v[5]*gB[10+d]);
        s[d]      = sinf(pmin);  s[5+d]  = cosf(pmin);
        s[10+d]   = sinf(pmax);  s[15+d] = cosf(pmax);
    }
    int cls = (int)v[6];
    const float4* ce = reinterpret_cast<const float4*>(cemb + (size_t)cls*64);
    float4* so = reinterpret_cast<float4*>(s + 20);
    #pragma unroll
    for (int i = 0; i < 16; ++i) so[i] = ce[i];
}

// ---------------- Stage B: encoder kernels (unchanged this round) ----------------
__global__ __launch_bounds__(256) void k_qkv8(const float* __restrict__ src,
        const float* __restrict__ w_in, const float* __restrict__ b_in,
        float* __restrict__ qkv, int lay)
{
    __shared__ float s8[8][D_];
    int r0 = blockIdx.x * 8, tid = threadIdx.x;
    for (int idx = tid; idx < 8*D_; idx += 256) {
        int r = idx / D_, d = idx - r*D_;
        s8[r][d] = src[(size_t)(r0+r)*D_ + d];
    }
    __syncthreads();
    if (tid < 3*D_) {
        const float* w = w_in + (size_t)lay*D_*3*D_ + tid;
        float acc[8] = {};
        for (int d = 0; d < D_; ++d) {
            float wv = w[(size_t)d*3*D_];
            #pragma unroll
            for (int r = 0; r < 8; ++r) acc[r] = fmaf(s8[r][d], wv, acc[r]);
        }
        float bv = b_in[lay*3*D_ + tid];
        #pragma unroll
        for (int r = 0; r < 8; ++r) qkv[(size_t)(r0+r)*(3*D_) + tid] = acc[r] + bv;
    }
}

__global__ __launch_bounds__(256) void k_attn(const float* __restrict__ qkv,
        const float* __restrict__ neg, float* __restrict__ attn_o)
{
    __shared__ float ks[L_*HD_], vs[L_*HD_], ns[L_];
    int b = blockIdx.x >> 2, h = blockIdx.x & 3;
    int tid = threadIdx.x;
    for (int idx = tid; idx < L_*HD_; idx += 256) {
        int l = idx / HD_, d = idx - l*HD_;
        size_t base = ((size_t)(b*L_ + l))*(3*D_) + h*HD_ + d;
        ks[idx] = qkv[base + D_];
        vs[idx] = qkv[base + 2*D_];
    }
    if (tid < L_) ns[tid] = neg[b*L_ + tid];
    __syncthreads();
    float q[HD_];
    {
        size_t base = ((size_t)(b*L_ + tid))*(3*D_) + h*HD_;
        #pragma unroll
        for (int d = 0; d < HD_; ++d) q[d] = qkv[base + d];
    }
    const float scale = 0.21821789023599239f;  // 1/sqrt(21)
    float m_run = -INFINITY, l_run = 0.0f;
    float o[HD_];
    #pragma unroll
    for (int d = 0; d < HD_; ++d) o[d] = 0.0f;
    for (int m = 0; m < L_; ++m) {
        const float* krow = &ks[m*HD_];
        float sdot = 0.0f;
        #pragma unroll
        for (int d = 0; d < HD_; ++d) sdot = fmaf(q[d], krow[d], sdot);
        float sc = sdot * scale + ns[m];
        float nm = fmaxf(m_run, sc);
        float c = __expf(m_run - nm);
        float p = __expf(sc - nm);
        l_run = l_run * c + p;
        const float* vrow = &vs[m*HD_];
        #pragma unroll
        for (int d = 0; d < HD_; ++d) o[d] = fmaf(p, vrow[d], o[d]*c);
        m_run = nm;
    }
    float inv = 1.0f / l_run;
    float* op = attn_o + ((size_t)(b*L_ + tid))*D_ + h*HD_;
    #pragma unroll
    for (int d = 0; d < HD_; ++d) op[d] = o[d]*inv;
}

__global__ __launch_bounds__(128) void k_oproj_ln(const float* __restrict__ attn_o,
        const float* __restrict__ w_out, const float* __restrict__ b_out,
        const float* __restrict__ ln_s, const float* __restrict__ ln_b,
        float* __restrict__ src, int lay)
{
    __shared__ float os[D_];
    __shared__ float r1[128], r2[128];
    int row = blockIdx.x, tid = threadIdx.x;
    if (tid < D_) os[tid] = attn_o[(size_t)row*D_ + tid];
    __syncthreads();
    float y = 0.0f;
    if (tid < D_) {
        const float* w = w_out + (size_t)lay*D_*D_ + tid;
        float acc = b_out[lay*D_ + tid];
        for (int d = 0; d < D_; ++d) acc = fmaf(os[d], w[(size_t)d*D_], acc);
        y = src[(size_t)row*D_ + tid] + acc;
    }
    r1[tid] = (tid < D_) ? y : 0.0f;
    r2[tid] = (tid < D_) ? y*y : 0.0f;
    __syncthreads();
    for (int s = 64; s > 0; s >>= 1) {
        if (tid < s) { r1[tid] += r1[tid+s]; r2[tid] += r2[tid+s]; }
        __syncthreads();
    }
    float mean = r1[0] * (1.0f/D_);
    float var  = r2[0] * (1.0f/D_) - mean*mean;
    float rstd = rsqrtf(var + 1e-5f);
    if (tid < D_)
        src[(size_t)row*D_ + tid] = (y - mean)*rstd*ln_s[lay*D_+tid] + ln_b[lay*D_+tid];
}

__global__ __launch_bounds__(256) void k_ff1(const float* __restrict__ src,
        const float* __restrict__ w_ff1, const float* __restrict__ b_ff1,
        float* __restrict__ hbuf, int lay)
{
    __shared__ float s8[8][D_];
    int r0 = blockIdx.x * 8, tid = threadIdx.x;
    for (int idx = tid; idx < 8*D_; idx += 256) {
        int r = idx / D_, d = idx - r*D_;
        s8[r][d] = src[(size_t)(r0+r)*D_ + d];
    }
    __syncthreads();
    float acc[8][4] = {};
    const float* w = w_ff1 + (size_t)lay*D_*DFF_;
    for (int d = 0; d < D_; ++d) {
        float wv[4];
        #pragma unroll
        for (int j = 0; j < 4; ++j) wv[j] = w[(size_t)d*DFF_ + tid + 256*j];
        #pragma unroll
        for (int r = 0; r < 8; ++r) {
            float sv = s8[r][d];
            #pragma unroll
            for (int j = 0; j < 4; ++j) acc[r][j] = fmaf(sv, wv[j], acc[r][j]);
        }
    }
    #pragma unroll
    for (int j = 0; j < 4; ++j) {
        float bv = b_ff1[lay*DFF_ + tid + 256*j];
        #pragma unroll
        for (int r = 0; r < 8; ++r)
            hbuf[(size_t)(r0+r)*DFF_ + tid + 256*j] = fmaxf(acc[r][j] + bv, 0.0f);
    }
}

__global__ __launch_bounds__(128) void k_ff2_ln(const float* __restrict__ hbuf,
        const float* __restrict__ w_ff2, const float* __restrict__ b_ff2,
        const float* __restrict__ ln_s, const float* __restrict__ ln_b,
        float* __restrict__ src, int lay)
{
    __shared__ __align__(16) float h8[8][DFF_];   // 32 KB
    __shared__ float r1[8][128], r2[8][128];
    int r0 = blockIdx.x * 8, tid = threadIdx.x;
    {
        const float4* hin = reinterpret_cast<const float4*>(hbuf + (size_t)r0*DFF_);
        float4* hs = reinterpret_cast<float4*>(&h8[0][0]);
        for (int idx = tid; idx < 8*DFF_/4; idx += 128) hs[idx] = hin[idx];
    }
    __syncthreads();
    float acc[8] = {};
    if (tid < D_) {
        const float* w = w_ff2 + (size_t)lay*DFF_*D_ + tid;
        for (int k = 0; k < DFF_; k += 4) {
            float wv[4];
            #pragma unroll
            for (int i = 0; i < 4; ++i) wv[i] = w[(size_t)(k+i)*D_];
            #pragma unroll
            for (int r = 0; r < 8; ++r) {
                float4 hv = *reinterpret_cast<const float4*>(&h8[r][k]);
                acc[r] += hv.x*wv[0] + hv.y*wv[1] + hv.z*wv[2] + hv.w*wv[3];
            }
        }
    }
    float y[8];
    float bv = (tid < D_) ? b_ff2[lay*D_ + tid] : 0.0f;
    #pragma unroll
    for (int r = 0; r < 8; ++r) {
        y[r] = (tid < D_) ? (src[(size_t)(r0+r)*D_ + tid] + acc[r] + bv) : 0.0f;
        r1[r][tid] = y[r];
        r2[r][tid] = y[r]*y[r];
    }
    __syncthreads();
    for (int s = 64; s > 0; s >>= 1) {
        if (tid < s) {
            #pragma unroll
            for (int r = 0; r < 8; ++r) { r1[r][tid] += r1[r][tid+s]; r2[r][tid] += r2[r][tid+s]; }
        }
        __syncthreads();
    }
    if (tid < D_) {
        #pragma unroll
        for (int r = 0; r < 8; ++r) {
            float mean = r1[r][0] * (1.0f/D_);
            float var  = r2[r][0] * (1.0f/D_) - mean*mean;
            float rstd = rsqrtf(var + 1e-5f);
            src[(size_t)(r0+r)*D_ + tid] = (y[r]-mean)*rstd*ln_s[lay*D_+tid] + ln_b[lay*D_+tid];
        }
    }
}

// ---------------- vis part (fp32, exact): 8 rows x w0_top ----------------
__global__ __launch_bounds__(256) void k_vis_gemm(const float* __restrict__ src,
        const float* __restrict__ w0, float* __restrict__ partials)
{
    __shared__ float vf[8*VCHUNK];   // 43 KB
    int nt = blockIdx.x, sp = blockIdx.y, tid = threadIdx.x;
    int k0 = sp * VCHUNK;
    for (int idx = tid; idx < 8*VCHUNK; idx += 256) {
        int r = idx / VCHUNK, c = idx - r*VCHUNK;
        vf[idx] = src[(size_t)r*VISF_ + k0 + c];
    }
    __syncthreads();
    int n = nt*128 + (tid & 127);
    int kh = tid >> 7;
    float acc[8] = {};
    const float* wp = w0 + (size_t)(k0 + kh*(VCHUNK/2))*DFF_ + n;
    const float* vp = vf + kh*(VCHUNK/2);
    for (int kk = 0; kk < VCHUNK/2; ++kk) {
        float w = wp[(size_t)kk*DFF_];
        #pragma unroll
        for (int m = 0; m < 8; ++m) acc[m] = fmaf(vp[m*VCHUNK + kk], w, acc[m]);
    }
    __syncthreads();
    float* red = vf;  // reuse LDS
    #pragma unroll
    for (int m = 0; m < 8; ++m) red[m*256 + tid] = acc[m];
    __syncthreads();
    if (kh == 0) {
        #pragma unroll
        for (int m = 0; m < 8; ++m)
            partials[(size_t)sp*(8*DFF_) + m*DFF_ + n] = red[m*256 + tid] + red[m*256 + tid + 128];
    }
}

__global__ void k_vis_reduce(const float* __restrict__ partials, float* __restrict__ vis)
{
    int o = blockIdx.x*256 + threadIdx.x;   // < 8192
    float s = 0.0f;
    for (int sp = 0; sp < VKS; ++sp) s += partials[(size_t)sp*8192 + o];
    vis[o] = s;
}

// ---------------- bf16 conversion helpers ----------------
struct bh4 { __hip_bfloat16 x, y, z, w; };

__global__ __launch_bounds__(256) void k_f2b(const float* __restrict__ in,
        __hip_bfloat16* __restrict__ out, int n4)
{
    int i = blockIdx.x*256 + threadIdx.x;
    if (i >= n4) return;
    float4 v = reinterpret_cast<const float4*>(in)[i];
    bh4 o = { __float2bfloat16(v.x), __float2bfloat16(v.y),
              __float2bfloat16(v.z), __float2bfloat16(v.w) };
    reinterpret_cast<bh4*>(out)[i] = o;
}

// transpose+convert: W[K][N] fp32 -> WT[N][K] bf16
__global__ __launch_bounds__(256) void k_wT(const float* __restrict__ W,
        __hip_bfloat16* __restrict__ WT, int K, int N)
{
    __shared__ float t[32][33];
    int kb = blockIdx.x*32, nb = blockIdx.y*32;
    int tx = threadIdx.x & 31, ty = threadIdx.x >> 5;   // ty 0..7
    #pragma unroll
    for (int i = 0; i < 4; ++i)
        t[ty + i*8][tx] = W[(size_t)(kb + ty + i*8)*N + nb + tx];
    __syncthreads();
    #pragma unroll
    for (int i = 0; i < 4; ++i)
        WT[(size_t)(nb + ty + i*8)*K + kb + tx] = __float2bfloat16(t[tx][ty + i*8]);
}

// ---------------- MFMA head GEMM (2-phase double-buffered) ----------------
// C[M=2048][N=1024] = relu(A[M][K]_bf16 @ WT[N][K]_bf16^T + bias (+ vis[bidx[m]]))
// BM=64, BN=128, BK=64, 8 waves (512 thr); wave computes 32x32 (2x2 frags).
// Double-buffered LDS; prefetch-next-then-compute so the __syncthreads'
// vmcnt(0) drain lands AFTER the MFMAs have covered the load latency.
template<bool ADD_VIS>
__global__ __launch_bounds__(512) void mfma_gemm(
        const __hip_bfloat16* __restrict__ A,   // [M][K]
        const __hip_bfloat16* __restrict__ WT,  // [N][K]
        const float* __restrict__ bias,         // [N]
        const float* __restrict__ vis,          // [8][1024]
        const int* __restrict__ bidx,           // [M]
        __hip_bfloat16* __restrict__ C,         // [M][N]
        int K)
{
    constexpr int N = 1024;
    __shared__ __align__(16) __hip_bfloat16 sA[2][4096];   // 2 x  8 KB
    __shared__ __align__(16) __hip_bfloat16 sB[2][8192];   // 2 x 16 KB
    int tid = threadIdx.x;
    int bm = blockIdx.x * 64, bn = blockIdx.y * 128;
    int wave = tid >> 6, lane = tid & 63;
    int wr = wave >> 2, wc = wave & 3;          // 2 x 4 wave grid
    int l15 = lane & 15, l4 = lane >> 4;
    f32x4 acc[2][2] = {};

    // per-thread staging coords (fixed): A 1 load, B 2 loads
    const int a_kb = tid >> 6,  a_m = tid & 63;
    const int b_kb0 = tid >> 7,       b_n0 = tid & 127;
    const int b_kb1 = (tid+512) >> 7, b_n1 = tid & 127;
    const __hip_bfloat16* Ap  = A  + (size_t)(bm + a_m)*K + a_kb*8;
    const __hip_bfloat16* Bp0 = WT + (size_t)(bn + b_n0)*K + b_kb0*8;
    const __hip_bfloat16* Bp1 = WT + (size_t)(bn + b_n1)*K + b_kb1*8;

    int nsteps = K >> 6;
    // prologue: stage tile 0 into buffer 0
    {
        gld_lds16(Ap,  (char*)&sA[0][0] + tid*16);
        gld_lds16(Bp0, (char*)&sB[0][0] + tid*16);
        gld_lds16(Bp1, (char*)&sB[0][0] + (tid+512)*16);
    }
    for (int t = 0; t < nsteps; ++t) {
        int cur = t & 1;
        __syncthreads();          // vmcnt(0): tile t resident; all waves past t-1 compute
        if (t + 1 < nsteps) {     // issue tile t+1 into the other buffer NOW
            int nb = cur ^ 1;
            int ko = (t+1) << 6;
            gld_lds16(Ap  + ko, (char*)&sA[nb][0] + tid*16);
            gld_lds16(Bp0 + ko, (char*)&sB[nb][0] + tid*16);
            gld_lds16(Bp1 + ko, (char*)&sB[nb][0] + (tid+512)*16);
        }
        const __hip_bfloat16* sa = &sA[cur][0];
        const __hip_bfloat16* sb = &sB[cur][0];
        #pragma unroll
        for (int ks = 0; ks < 2; ++ks) {
            bf16x8 af[2], bfr[2];
            #pragma unroll
            for (int mi = 0; mi < 2; ++mi)
                af[mi] = *reinterpret_cast<const bf16x8*>(
                    &sa[(size_t)((ks*4 + l4)*64 + wr*32 + mi*16 + l15) * 8]);
            #pragma unroll
            for (int ni = 0; ni < 2; ++ni)
                bfr[ni] = *reinterpret_cast<const bf16x8*>(
                    &sb[(size_t)((ks*4 + l4)*128 + wc*32 + ni*16 + l15) * 8]);
            #pragma unroll
            for (int mi = 0; mi < 2; ++mi)
                #pragma unroll
                for (int ni = 0; ni < 2; ++ni)
                    acc[mi][ni] = __builtin_amdgcn_mfma_f32_16x16x32_bf16(
                        af[mi], bfr[ni], acc[mi][ni], 0, 0, 0);
        }
    }

    // epilogue: D[row=(lane>>4)*4+reg][col=lane&15] per frag (m89-verified)
    #pragma unroll
    for (int mi = 0; mi < 2; ++mi) {
        #pragma unroll
        for (int reg = 0; reg < 4; ++reg) {
            int row = bm + wr*32 + mi*16 + l4*4 + reg;
            const float* vrow = nullptr;
            if (ADD_VIS) vrow = vis + (size_t)bidx[row]*1024;
            #pragma unroll
            for (int ni = 0; ni < 2; ++ni) {
                int col = bn + wc*32 + ni*16 + l15;
                float v = acc[mi][ni][reg] + bias[col];
                if (ADD_VIS) v += vrow[col];
                v = fmaxf(v, 0.0f);
                C[(size_t)row*N + col] = __float2bfloat16(v);
            }
        }
    }
}

// final 1024 -> 6 (bf16 h)
__global__ __launch_bounds__(64) void k_final(const __hip_bfloat16* __restrict__ h,
        const float* __restrict__ w4, const float* __restrict__ b4, float* __restrict__ out)
{
    int t = blockIdx.x, lane = threadIdx.x;
    float acc[6] = {};
    for (int k = lane; k < DFF_; k += 64) {
        float hv = __bfloat162float(h[(size_t)t*DFF_ + k]);
        #pragma unroll
        for (int j = 0; j < 6; ++j) acc[j] = fmaf(hv, w4[k*6 + j], acc[j]);
    }
    #pragma unroll
    for (int j = 0; j < 6; ++j)
        #pragma unroll
        for (int s = 32; s > 0; s >>= 1) acc[j] += __shfl_down(acc[j], s);
    if (lane == 0) {
        #pragma unroll
        for (int j = 0; j < 6; ++j) out[(size_t)t*6 + j] = acc[j] + b4[j];
    }
}

extern "C" void kernel_launch(void* const* d_in, const int* in_sizes, int n_in,
                              void* d_out, int out_size, void* d_ws, size_t ws_size,
                              hipStream_t stream)
{
    const float* grd   = (const float*)d_in[0];
    const float* vfeat = (const float*)d_in[1];
    const int*   tbi   = (const int*)  d_in[2];
    const float* gB    = (const float*)d_in[3];
    const float* cemb  = (const float*)d_in[4];
    const float* w_in  = (const float*)d_in[5];
    const float* b_in  = (const float*)d_in[6];
    const float* w_out = (const float*)d_in[7];
    const float* b_out = (const float*)d_in[8];
    const float* ln1_s = (const float*)d_in[9];
    const float* ln1_b = (const float*)d_in[10];
    const float* w_ff1 = (const float*)d_in[11];
    const float* b_ff1 = (const float*)d_in[12];
    const float* w_ff2 = (const float*)d_in[13];
    const float* b_ff2 = (const float*)d_in[14];
    const float* ln2_s = (const float*)d_in[15];
    const float* ln2_b = (const float*)d_in[16];
    const float* w0    = (const float*)d_in[17];
    const float* b0    = (const float*)d_in[18];
    const float* w1    = (const float*)d_in[19];
    const float* b1    = (const float*)d_in[20];
    const float* w2    = (const float*)d_in[21];
    const float* b2    = (const float*)d_in[22];
    const float* w3    = (const float*)d_in[23];
    const float* b3    = (const float*)d_in[24];
    const float* w4    = (const float*)d_in[25];
    const float* b4    = (const float*)d_in[26];

    float* ws = (float*)d_ws;
    float* src    = ws;                       // 172032
    float* neg    = src    + 172032;          // 2048
    float* qkv    = neg    + 2048;            // 516096
    float* attn_o = qkv    + 516096;          // 172032
    float* hbuf   = attn_o + 172032;          // 2097152
    float* parts  = hbuf   + 2097152;         // 131072
    float* visp   = parts  + 131072;          // 8192
    float* fend   = visp   + 8192;            // fp32 region: ~12.4 MB
    __hip_bfloat16* grdb = (__hip_bfloat16*)fend;        // 8388608
    __hip_bfloat16* w0t  = grdb + 8388608;               // 4194304
    __hip_bfloat16* w1t  = w0t  + 4194304;               // 1048576
    __hip_bfloat16* w2t  = w1t  + 1048576;               // 1048576
    __hip_bfloat16* w3t  = w2t  + 1048576;               // 1048576
    __hip_bfloat16* hab  = w3t  + 1048576;               // 2097152
    __hip_bfloat16* hbb  = hab  + 2097152;               // 2097152  (total ~52.3 MB)

    // conversions (independent of encoder; issue first)
    k_f2b<<<(T_*LM_/4 + 255)/256, 256, 0, stream>>>(grd, grdb, T_*LM_/4);
    k_wT<<<dim3(LM_/32,  DFF_/32), 256, 0, stream>>>(w0 + (size_t)VISF_*DFF_, w0t, LM_,  DFF_);
    k_wT<<<dim3(DFF_/32, DFF_/32), 256, 0, stream>>>(w1, w1t, DFF_, DFF_);
    k_wT<<<dim3(DFF_/32, DFF_/32), 256, 0, stream>>>(w2, w2t, DFF_, DFF_);
    k_wT<<<dim3(DFF_/32, DFF_/32), 256, 0, stream>>>(w3, w3t, DFF_, DFF_);

    k_build_src<<<8, 256, 0, stream>>>(vfeat, gB, cemb, src, neg);

    for (int lay = 0; lay < 2; ++lay) {
        k_qkv8    <<<BL_/8, 256, 0, stream>>>(src, w_in, b_in, qkv, lay);
        k_attn    <<<B_*H_, 256, 0, stream>>>(qkv, neg, attn_o);
        k_oproj_ln<<<BL_,   128, 0, stream>>>(attn_o, w_out, b_out, ln1_s, ln1_b, src, lay);
        k_ff1     <<<BL_/8, 256, 0, stream>>>(src, w_ff1, b_ff1, hbuf, lay);
        k_ff2_ln  <<<BL_/8, 128, 0, stream>>>(hbuf, w_ff2, b_ff2, ln2_s, ln2_b, src, lay);
    }

    k_vis_gemm  <<<dim3(8, VKS), 256, 0, stream>>>(src, w0, parts);
    k_vis_reduce<<<32, 256, 0, stream>>>(parts, visp);

    dim3 mg(T_/64, DFF_/128);   // (32, 8)
    mfma_gemm<true ><<<mg, 512, 0, stream>>>(grdb, w0t, b0, visp, tbi, hab, LM_);
    mfma_gemm<false><<<mg, 512, 0, stream>>>(hab,  w1t, b1, nullptr, nullptr, hbb, DFF_);
    mfma_gemm<false><<<mg, 512, 0, stream>>>(hbb,  w2t, b2, nullptr, nullptr, hab, DFF_);
    mfma_gemm<false><<<mg, 512, 0, stream>>>(hab,  w3t, b3, nullptr, nullptr, hbb, DFF_);

    k_final<<<T_, 64, 0, stream>>>(hbb, w4, b4, (float*)d_out);
}

// Round 4
// 440.758 us; speedup vs baseline: 2.1189x; 1.2292x over previous
//
#include <hip/hip_runtime.h>
#include <hip/hip_bf16.h>

#define B_ 8
#define L_ 256
#define T_ 2048
#define LM_ 4096
#define DFF_ 1024
#define D_ 84
#define H_ 4
#define HD_ 21
#define BL_ (B_*L_)          // 2048
#define VISF_ (L_*D_)        // 21504
#define VKS 16
#define VCHUNK (VISF_/VKS)   // 1344

typedef __attribute__((ext_vector_type(8))) short bf16x8;
typedef __attribute__((ext_vector_type(4))) float f32x4;

typedef const __attribute__((address_space(1))) int* gas_p;
typedef __attribute__((address_space(3))) int* las_p;
__device__ __forceinline__ void gld_lds16(const void* g, void* l) {
    __builtin_amdgcn_global_load_lds((gas_p)g, (las_p)l, 16, 0, 0);
}

// ---------------- Stage A: build src + pad bias ----------------
__global__ void k_build_src(const float* __restrict__ vf, const float* __restrict__ gB,
                            const float* __restrict__ cemb, float* __restrict__ src,
                            float* __restrict__ neg)
{
    int row = blockIdx.x * blockDim.x + threadIdx.x;
    if (row >= BL_) return;
    float v[7];
    bool allz = true;
    #pragma unroll
    for (int c = 0; c < 7; ++c) { v[c] = vf[row*7 + c]; allz = allz && (v[c] == 0.0f); }
    neg[row] = allz ? -1e9f : 0.0f;
    float* s = src + (size_t)row * D_;
    const float TWO_PI = 6.28318530717958647692f;
    #pragma unroll
    for (int d = 0; d < 5; ++d) {
        float pmin = TWO_PI * (v[0]*gB[d] + v[1]*gB[5+d] + v[2]*gB[10+d]);
        float pmax = TWO_PI * (v[3]*gB[d] + v[4]*gB[5+d] + v[5]*gB[10+d]);
        s[d]      = sinf(pmin);  s[5+d]  = cosf(pmin);
        s[10+d]   = sinf(pmax);  s[15+d] = cosf(pmax);
    }
    int cls = (int)v[6];
    const float4* ce = reinterpret_cast<const float4*>(cemb + (size_t)cls*64);
    float4* so = reinterpret_cast<float4*>(s + 20);
    #pragma unroll
    for (int i = 0; i < 16; ++i) so[i] = ce[i];
}

// ---------------- Stage B: encoder ----------------
__global__ __launch_bounds__(256) void k_qkv8(const float* __restrict__ src,
        const float* __restrict__ w_in, const float* __restrict__ b_in,
        float* __restrict__ qkv, int lay)
{
    __shared__ float s8[8][D_];
    int r0 = blockIdx.x * 8, tid = threadIdx.x;
    for (int idx = tid; idx < 8*D_; idx += 256) {
        int r = idx / D_, d = idx - r*D_;
        s8[r][d] = src[(size_t)(r0+r)*D_ + d];
    }
    __syncthreads();
    if (tid < 3*D_) {
        const float* w = w_in + (size_t)lay*D_*3*D_ + tid;
        float acc[8] = {};
        for (int d = 0; d < D_; ++d) {
            float wv = w[(size_t)d*3*D_];
            #pragma unroll
            for (int r = 0; r < 8; ++r) acc[r] = fmaf(s8[r][d], wv, acc[r]);
        }
        float bv = b_in[lay*3*D_ + tid];
        #pragma unroll
        for (int r = 0; r < 8; ++r) qkv[(size_t)(r0+r)*(3*D_) + tid] = acc[r] + bv;
    }
}

__global__ __launch_bounds__(256) void k_attn(const float* __restrict__ qkv,
        const float* __restrict__ neg, float* __restrict__ attn_o)
{
    __shared__ float ks[L_*HD_], vs[L_*HD_], ns[L_];
    int b = blockIdx.x >> 2, h = blockIdx.x & 3;
    int tid = threadIdx.x;
    for (int idx = tid; idx < L_*HD_; idx += 256) {
        int l = idx / HD_, d = idx - l*HD_;
        size_t base = ((size_t)(b*L_ + l))*(3*D_) + h*HD_ + d;
        ks[idx] = qkv[base + D_];
        vs[idx] = qkv[base + 2*D_];
    }
    if (tid < L_) ns[tid] = neg[b*L_ + tid];
    __syncthreads();
    float q[HD_];
    {
        size_t base = ((size_t)(b*L_ + tid))*(3*D_) + h*HD_;
        #pragma unroll
        for (int d = 0; d < HD_; ++d) q[d] = qkv[base + d];
    }
    const float scale = 0.21821789023599239f;  // 1/sqrt(21)
    float m_run = -INFINITY, l_run = 0.0f;
    float o[HD_];
    #pragma unroll
    for (int d = 0; d < HD_; ++d) o[d] = 0.0f;
    for (int m = 0; m < L_; ++m) {
        const float* krow = &ks[m*HD_];
        float sdot = 0.0f;
        #pragma unroll
        for (int d = 0; d < HD_; ++d) sdot = fmaf(q[d], krow[d], sdot);
        float sc = sdot * scale + ns[m];
        float nm = fmaxf(m_run, sc);
        float c = __expf(m_run - nm);
        float p = __expf(sc - nm);
        l_run = l_run * c + p;
        const float* vrow = &vs[m*HD_];
        #pragma unroll
        for (int d = 0; d < HD_; ++d) o[d] = fmaf(p, vrow[d], o[d]*c);
        m_run = nm;
    }
    float inv = 1.0f / l_run;
    float* op = attn_o + ((size_t)(b*L_ + tid))*D_ + h*HD_;
    #pragma unroll
    for (int d = 0; d < HD_; ++d) op[d] = o[d]*inv;
}

// out-proj + residual + LN; also emits bf16 K-padded src for FF1 MFMA
__global__ __launch_bounds__(128) void k_oproj_ln(const float* __restrict__ attn_o,
        const float* __restrict__ w_out, const float* __restrict__ b_out,
        const float* __restrict__ ln_s, const float* __restrict__ ln_b,
        float* __restrict__ src, __hip_bfloat16* __restrict__ srcb, int lay)
{
    __shared__ float os[D_];
    __shared__ float r1[128], r2[128];
    int row = blockIdx.x, tid = threadIdx.x;
    if (tid < D_) os[tid] = attn_o[(size_t)row*D_ + tid];
    __syncthreads();
    float y = 0.0f;
    if (tid < D_) {
        const float* w = w_out + (size_t)lay*D_*D_ + tid;
        float acc = b_out[lay*D_ + tid];
        for (int d = 0; d < D_; ++d) acc = fmaf(os[d], w[(size_t)d*D_], acc);
        y = src[(size_t)row*D_ + tid] + acc;
    }
    r1[tid] = (tid < D_) ? y : 0.0f;
    r2[tid] = (tid < D_) ? y*y : 0.0f;
    __syncthreads();
    for (int s = 64; s > 0; s >>= 1) {
        if (tid < s) { r1[tid] += r1[tid+s]; r2[tid] += r2[tid+s]; }
        __syncthreads();
    }
    float mean = r1[0] * (1.0f/D_);
    float var  = r2[0] * (1.0f/D_) - mean*mean;
    float rstd = rsqrtf(var + 1e-5f);
    float out = 0.0f;
    if (tid < D_) {
        out = (y - mean)*rstd*ln_s[lay*D_+tid] + ln_b[lay*D_+tid];
        src[(size_t)row*D_ + tid] = out;
    }
    srcb[(size_t)row*128 + tid] = (tid < D_) ? __float2bfloat16(out)
                                             : __float2bfloat16(0.0f);
}

// FF2 split-K MFMA: part[sp][2048][96] = hb[2048][1024]_slice @ wff2t[96][1024]^T
__global__ __launch_bounds__(256) void k_ff2_mfma(
        const __hip_bfloat16* __restrict__ hb,     // [2048][1024]
        const __hip_bfloat16* __restrict__ wt,     // [96][1024]
        float* __restrict__ part)                  // [8][2048][96]
{
    __shared__ __align__(16) __hip_bfloat16 sA[2][4096];   // 64m x 64k
    __shared__ __align__(16) __hip_bfloat16 sB[2][6144];   // 96n x 64k
    int tid = threadIdx.x;
    int bm = blockIdx.x * 64, sp = blockIdx.y;
    int wave = tid >> 6, lane = tid & 63;
    int wr = wave >> 1, wc = wave & 1;          // 2x2 waves: 32m x 48n each
    int l15 = lane & 15, l4 = lane >> 4;
    f32x4 acc[2][3] = {};

    const int a_kb0 = tid >> 6,       a_m0 = tid & 63;
    const int a_kb1 = (tid+256) >> 6, a_m1 = tid & 63;
    const int b_i0 = tid,       b_kb0 = b_i0/96, b_n0 = b_i0%96;
    const int b_i1 = tid + 256, b_kb1 = b_i1/96, b_n1 = b_i1%96;
    const int b_i2 = tid + 512, b_kb2 = b_i2/96, b_n2 = b_i2%96;
    const __hip_bfloat16* Ap0 = hb + (size_t)(bm + a_m0)*1024 + sp*128 + a_kb0*8;
    const __hip_bfloat16* Ap1 = hb + (size_t)(bm + a_m1)*1024 + sp*128 + a_kb1*8;
    const __hip_bfloat16* Bp0 = wt + (size_t)b_n0*1024 + sp*128 + b_kb0*8;
    const __hip_bfloat16* Bp1 = wt + (size_t)b_n1*1024 + sp*128 + b_kb1*8;
    const __hip_bfloat16* Bp2 = wt + (size_t)b_n2*1024 + sp*128 + b_kb2*8;

    // prologue: stage step 0
    gld_lds16(Ap0, (char*)&sA[0][0] + tid*16);
    gld_lds16(Ap1, (char*)&sA[0][0] + (tid+256)*16);
    gld_lds16(Bp0, (char*)&sB[0][0] + b_i0*16);
    gld_lds16(Bp1, (char*)&sB[0][0] + b_i1*16);
    gld_lds16(Bp2, (char*)&sB[0][0] + b_i2*16);
    #pragma unroll
    for (int t = 0; t < 2; ++t) {
        __syncthreads();
        if (t == 0) {
            gld_lds16(Ap0 + 64, (char*)&sA[1][0] + tid*16);
            gld_lds16(Ap1 + 64, (char*)&sA[1][0] + (tid+256)*16);
            gld_lds16(Bp0 + 64, (char*)&sB[1][0] + b_i0*16);
            gld_lds16(Bp1 + 64, (char*)&sB[1][0] + b_i1*16);
            gld_lds16(Bp2 + 64, (char*)&sB[1][0] + b_i2*16);
        }
        const __hip_bfloat16* sa = &sA[t][0];
        const __hip_bfloat16* sb = &sB[t][0];
        #pragma unroll
        for (int ks = 0; ks < 2; ++ks) {
            bf16x8 af[2], bfr[3];
            #pragma unroll
            for (int mi = 0; mi < 2; ++mi)
                af[mi] = *reinterpret_cast<const bf16x8*>(
                    &sa[(size_t)((ks*4 + l4)*64 + wr*32 + mi*16 + l15) * 8]);
            #pragma unroll
            for (int ni = 0; ni < 3; ++ni)
                bfr[ni] = *reinterpret_cast<const bf16x8*>(
                    &sb[(size_t)((ks*4 + l4)*96 + wc*48 + ni*16 + l15) * 8]);
            #pragma unroll
            for (int mi = 0; mi < 2; ++mi)
                #pragma unroll
                for (int ni = 0; ni < 3; ++ni)
                    acc[mi][ni] = __builtin_amdgcn_mfma_f32_16x16x32_bf16(
                        af[mi], bfr[ni], acc[mi][ni], 0, 0, 0);
        }
    }
    float* po = part + (size_t)sp*(2048*96);
    #pragma unroll
    for (int mi = 0; mi < 2; ++mi)
        #pragma unroll
        for (int reg = 0; reg < 4; ++reg) {
            int row = bm + wr*32 + mi*16 + l4*4 + reg;
            #pragma unroll
            for (int ni = 0; ni < 3; ++ni) {
                int col = wc*48 + ni*16 + l15;
                po[(size_t)row*96 + col] = acc[mi][ni][reg];
            }
        }
}

// reduce split-K partials + bias + residual + LN (over the true 84 cols)
__global__ __launch_bounds__(128) void k_ff2ln_red(const float* __restrict__ part,
        const float* __restrict__ b_ff2, const float* __restrict__ ln_s,
        const float* __restrict__ ln_b, float* __restrict__ src, int lay)
{
    __shared__ float r1[128], r2[128];
    int row = blockIdx.x, tid = threadIdx.x;
    float y = 0.0f;
    if (tid < D_) {
        #pragma unroll
        for (int sp = 0; sp < 8; ++sp)
            y += part[(size_t)sp*(2048*96) + (size_t)row*96 + tid];
        y += b_ff2[lay*D_ + tid] + src[(size_t)row*D_ + tid];
    }
    r1[tid] = (tid < D_) ? y : 0.0f;
    r2[tid] = (tid < D_) ? y*y : 0.0f;
    __syncthreads();
    for (int s = 64; s > 0; s >>= 1) {
        if (tid < s) { r1[tid] += r1[tid+s]; r2[tid] += r2[tid+s]; }
        __syncthreads();
    }
    float mean = r1[0] * (1.0f/D_);
    float var  = r2[0] * (1.0f/D_) - mean*mean;
    float rstd = rsqrtf(var + 1e-5f);
    if (tid < D_)
        src[(size_t)row*D_ + tid] = (y - mean)*rstd*ln_s[lay*D_+tid] + ln_b[lay*D_+tid];
}

// ---------------- vis part (fp32, exact): 8 rows x w0_top ----------------
__global__ __launch_bounds__(256) void k_vis_gemm(const float* __restrict__ src,
        const float* __restrict__ w0, float* __restrict__ partials)
{
    __shared__ float vf[8*VCHUNK];   // 43 KB
    int nt = blockIdx.x, sp = blockIdx.y, tid = threadIdx.x;
    int k0 = sp * VCHUNK;
    for (int idx = tid; idx < 8*VCHUNK; idx += 256) {
        int r = idx / VCHUNK, c = idx - r*VCHUNK;
        vf[idx] = src[(size_t)r*VISF_ + k0 + c];
    }
    __syncthreads();
    int n = nt*128 + (tid & 127);
    int kh = tid >> 7;
    float acc[8] = {};
    const float* wp = w0 + (size_t)(k0 + kh*(VCHUNK/2))*DFF_ + n;
    const float* vp = vf + kh*(VCHUNK/2);
    for (int kk = 0; kk < VCHUNK/2; ++kk) {
        float w = wp[(size_t)kk*DFF_];
        #pragma unroll
        for (int m = 0; m < 8; ++m) acc[m] = fmaf(vp[m*VCHUNK + kk], w, acc[m]);
    }
    __syncthreads();
    float* red = vf;  // reuse LDS
    #pragma unroll
    for (int m = 0; m < 8; ++m) red[m*256 + tid] = acc[m];
    __syncthreads();
    if (kh == 0) {
        #pragma unroll
        for (int m = 0; m < 8; ++m)
            partials[(size_t)sp*(8*DFF_) + m*DFF_ + n] = red[m*256 + tid] + red[m*256 + tid + 128];
    }
}

__global__ void k_vis_reduce(const float* __restrict__ partials, float* __restrict__ vis)
{
    int o = blockIdx.x*256 + threadIdx.x;   // < 8192
    float s = 0.0f;
    for (int sp = 0; sp < VKS; ++sp) s += partials[(size_t)sp*8192 + o];
    vis[o] = s;
}

// ---------------- bf16 conversion helpers ----------------
struct bh4 { __hip_bfloat16 x, y, z, w; };

__global__ __launch_bounds__(256) void k_f2b(const float* __restrict__ in,
        __hip_bfloat16* __restrict__ out, int n4)
{
    int i = blockIdx.x*256 + threadIdx.x;
    if (i >= n4) return;
    float4 v = reinterpret_cast<const float4*>(in)[i];
    bh4 o = { __float2bfloat16(v.x), __float2bfloat16(v.y),
              __float2bfloat16(v.z), __float2bfloat16(v.w) };
    reinterpret_cast<bh4*>(out)[i] = o;
}

// transpose+convert: W[K][N] fp32 -> WT[N][K] bf16 (exact multiples of 32)
__global__ __launch_bounds__(256) void k_wT(const float* __restrict__ W,
        __hip_bfloat16* __restrict__ WT, int K, int N)
{
    __shared__ float t[32][33];
    int kb = blockIdx.x*32, nb = blockIdx.y*32;
    int tx = threadIdx.x & 31, ty = threadIdx.x >> 5;   // ty 0..7
    #pragma unroll
    for (int i = 0; i < 4; ++i)
        t[ty + i*8][tx] = W[(size_t)(kb + ty + i*8)*N + nb + tx];
    __syncthreads();
    #pragma unroll
    for (int i = 0; i < 4; ++i)
        WT[(size_t)(nb + ty + i*8)*K + kb + tx] = __float2bfloat16(t[tx][ty + i*8]);
}

// padded transpose+convert: W[K][N] fp32 -> WT[NP][KP] bf16, zero-filled
__global__ __launch_bounds__(256) void k_wTp(const float* __restrict__ W,
        __hip_bfloat16* __restrict__ WT, int K, int N, int KP)
{
    __shared__ float t[32][33];
    int kb = blockIdx.x*32, nb = blockIdx.y*32;
    int tx = threadIdx.x & 31, ty = threadIdx.x >> 5;
    #pragma unroll
    for (int i = 0; i < 4; ++i) {
        int k = kb + ty + i*8, n = nb + tx;
        t[ty + i*8][tx] = (k < K && n < N) ? W[(size_t)k*N + n] : 0.0f;
    }
    __syncthreads();
    #pragma unroll
    for (int i = 0; i < 4; ++i)
        WT[(size_t)(nb + ty + i*8)*KP + kb + tx] = __float2bfloat16(t[tx][ty + i*8]);
}

// ---------------- MFMA GEMM (2-phase double-buffered) ----------------
// C[M][N=1024] = relu(A[M][K]_bf16 @ WT[N][K]_bf16^T + bias (+ vis[bidx[m]]))
template<bool ADD_VIS>
__global__ __launch_bounds__(512) void mfma_gemm(
        const __hip_bfloat16* __restrict__ A,   // [M][K]
        const __hip_bfloat16* __restrict__ WT,  // [N][K]
        const float* __restrict__ bias,         // [N]
        const float* __restrict__ vis,          // [8][1024]
        const int* __restrict__ bidx,           // [M]
        __hip_bfloat16* __restrict__ C,         // [M][N]
        int K)
{
    constexpr int N = 1024;
    __shared__ __align__(16) __hip_bfloat16 sA[2][4096];   // 2 x  8 KB
    __shared__ __align__(16) __hip_bfloat16 sB[2][8192];   // 2 x 16 KB
    int tid = threadIdx.x;
    int bm = blockIdx.x * 64, bn = blockIdx.y * 128;
    int wave = tid >> 6, lane = tid & 63;
    int wr = wave >> 2, wc = wave & 3;          // 2 x 4 wave grid
    int l15 = lane & 15, l4 = lane >> 4;
    f32x4 acc[2][2] = {};

    const int a_kb = tid >> 6,  a_m = tid & 63;
    const int b_kb0 = tid >> 7,       b_n0 = tid & 127;
    const int b_kb1 = (tid+512) >> 7, b_n1 = tid & 127;
    const __hip_bfloat16* Ap  = A  + (size_t)(bm + a_m)*K + a_kb*8;
    const __hip_bfloat16* Bp0 = WT + (size_t)(bn + b_n0)*K + b_kb0*8;
    const __hip_bfloat16* Bp1 = WT + (size_t)(bn + b_n1)*K + b_kb1*8;

    int nsteps = K >> 6;
    gld_lds16(Ap,  (char*)&sA[0][0] + tid*16);
    gld_lds16(Bp0, (char*)&sB[0][0] + tid*16);
    gld_lds16(Bp1, (char*)&sB[0][0] + (tid+512)*16);
    for (int t = 0; t < nsteps; ++t) {
        int cur = t & 1;
        __syncthreads();          // vmcnt(0): tile t resident
        if (t + 1 < nsteps) {     // issue tile t+1 now; MFMAs cover the latency
            int nb = cur ^ 1;
            int ko = (t+1) << 6;
            gld_lds16(Ap  + ko, (char*)&sA[nb][0] + tid*16);
            gld_lds16(Bp0 + ko, (char*)&sB[nb][0] + tid*16);
            gld_lds16(Bp1 + ko, (char*)&sB[nb][0] + (tid+512)*16);
        }
        const __hip_bfloat16* sa = &sA[cur][0];
        const __hip_bfloat16* sb = &sB[cur][0];
        #pragma unroll
        for (int ks = 0; ks < 2; ++ks) {
            bf16x8 af[2], bfr[2];
            #pragma unroll
            for (int mi = 0; mi < 2; ++mi)
                af[mi] = *reinterpret_cast<const bf16x8*>(
                    &sa[(size_t)((ks*4 + l4)*64 + wr*32 + mi*16 + l15) * 8]);
            #pragma unroll
            for (int ni = 0; ni < 2; ++ni)
                bfr[ni] = *reinterpret_cast<const bf16x8*>(
                    &sb[(size_t)((ks*4 + l4)*128 + wc*32 + ni*16 + l15) * 8]);
            #pragma unroll
            for (int mi = 0; mi < 2; ++mi)
                #pragma unroll
                for (int ni = 0; ni < 2; ++ni)
                    acc[mi][ni] = __builtin_amdgcn_mfma_f32_16x16x32_bf16(
                        af[mi], bfr[ni], acc[mi][ni], 0, 0, 0);
        }
    }

    #pragma unroll
    for (int mi = 0; mi < 2; ++mi) {
        #pragma unroll
        for (int reg = 0; reg < 4; ++reg) {
            int row = bm + wr*32 + mi*16 + l4*4 + reg;
            const float* vrow = nullptr;
            if (ADD_VIS) vrow = vis + (size_t)bidx[row]*1024;
            #pragma unroll
            for (int ni = 0; ni < 2; ++ni) {
                int col = bn + wc*32 + ni*16 + l15;
                float v = acc[mi][ni][reg] + bias[col];
                if (ADD_VIS) v += vrow[col];
                v = fmaxf(v, 0.0f);
                C[(size_t)row*N + col] = __float2bfloat16(v);
            }
        }
    }
}

// final 1024 -> 6 (bf16 h)
__global__ __launch_bounds__(64) void k_final(const __hip_bfloat16* __restrict__ h,
        const float* __restrict__ w4, const float* __restrict__ b4, float* __restrict__ out)
{
    int t = blockIdx.x, lane = threadIdx.x;
    float acc[6] = {};
    for (int k = lane; k < DFF_; k += 64) {
        float hv = __bfloat162float(h[(size_t)t*DFF_ + k]);
        #pragma unroll
        for (int j = 0; j < 6; ++j) acc[j] = fmaf(hv, w4[k*6 + j], acc[j]);
    }
    #pragma unroll
    for (int j = 0; j < 6; ++j)
        #pragma unroll
        for (int s = 32; s > 0; s >>= 1) acc[j] += __shfl_down(acc[j], s);
    if (lane == 0) {
        #pragma unroll
        for (int j = 0; j < 6; ++j) out[(size_t)t*6 + j] = acc[j] + b4[j];
    }
}

extern "C" void kernel_launch(void* const* d_in, const int* in_sizes, int n_in,
                              void* d_out, int out_size, void* d_ws, size_t ws_size,
                              hipStream_t stream)
{
    const float* grd   = (const float*)d_in[0];
    const float* vfeat = (const float*)d_in[1];
    const int*   tbi   = (const int*)  d_in[2];
    const float* gB    = (const float*)d_in[3];
    const float* cemb  = (const float*)d_in[4];
    const float* w_in  = (const float*)d_in[5];
    const float* b_in  = (const float*)d_in[6];
    const float* w_out = (const float*)d_in[7];
    const float* b_out = (const float*)d_in[8];
    const float* ln1_s = (const float*)d_in[9];
    const float* ln1_b = (const float*)d_in[10];
    const float* w_ff1 = (const float*)d_in[11];
    const float* b_ff1 = (const float*)d_in[12];
    const float* w_ff2 = (const float*)d_in[13];
    const float* b_ff2 = (const float*)d_in[14];
    const float* ln2_s = (const float*)d_in[15];
    const float* ln2_b = (const float*)d_in[16];
    const float* w0    = (const float*)d_in[17];
    const float* b0    = (const float*)d_in[18];
    const float* w1    = (const float*)d_in[19];
    const float* b1    = (const float*)d_in[20];
    const float* w2    = (const float*)d_in[21];
    const float* b2    = (const float*)d_in[22];
    const float* w3    = (const float*)d_in[23];
    const float* b3    = (const float*)d_in[24];
    const float* w4    = (const float*)d_in[25];
    const float* b4    = (const float*)d_in[26];

    float* ws = (float*)d_ws;
    float* src    = ws;                       // 172032
    float* neg    = src    + 172032;          // 2048
    float* qkv    = neg    + 2048;            // 516096
    float* attn_o = qkv    + 516096;          // 172032
    float* vparts = attn_o + 172032;          // 131072
    float* visp   = vparts + 131072;          // 8192
    float* ffpart = visp   + 8192;            // 8*2048*96 = 1572864
    float* fend   = ffpart + 1572864;
    __hip_bfloat16* grdb  = (__hip_bfloat16*)fend;       // 8388608
    __hip_bfloat16* w0t   = grdb  + 8388608;             // 4194304
    __hip_bfloat16* w1t   = w0t   + 4194304;             // 1048576
    __hip_bfloat16* w2t   = w1t   + 1048576;             // 1048576
    __hip_bfloat16* w3t   = w2t   + 1048576;             // 1048576
    __hip_bfloat16* hab   = w3t   + 1048576;             // 2097152
    __hip_bfloat16* hbb   = hab   + 2097152;             // 2097152
    __hip_bfloat16* srcb  = hbb   + 2097152;             // 2048*128 = 262144
    __hip_bfloat16* wff1t = srcb  + 262144;              // 2*1024*128 = 262144
    __hip_bfloat16* wff2t = wff1t + 262144;              // 2*96*1024 = 196608
    __hip_bfloat16* ffh   = hab;  // alias: hab unused until head GEMMs

    // conversions (independent of encoder; issue first)
    k_f2b<<<(T_*LM_/4 + 255)/256, 256, 0, stream>>>(grd, grdb, T_*LM_/4);
    k_wT<<<dim3(LM_/32,  DFF_/32), 256, 0, stream>>>(w0 + (size_t)VISF_*DFF_, w0t, LM_,  DFF_);
    k_wT<<<dim3(DFF_/32, DFF_/32), 256, 0, stream>>>(w1, w1t, DFF_, DFF_);
    k_wT<<<dim3(DFF_/32, DFF_/32), 256, 0, stream>>>(w2, w2t, DFF_, DFF_);
    k_wT<<<dim3(DFF_/32, DFF_/32), 256, 0, stream>>>(w3, w3t, DFF_, DFF_);
    for (int l = 0; l < 2; ++l) {
        k_wTp<<<dim3(128/32, 1024/32), 256, 0, stream>>>(
            w_ff1 + (size_t)l*D_*DFF_, wff1t + (size_t)l*1024*128, D_, DFF_, 128);
        k_wTp<<<dim3(1024/32, 96/32),  256, 0, stream>>>(
            w_ff2 + (size_t)l*DFF_*D_, wff2t + (size_t)l*96*1024, DFF_, D_, 1024);
    }

    k_build_src<<<8, 256, 0, stream>>>(vfeat, gB, cemb, src, neg);

    for (int lay = 0; lay < 2; ++lay) {
        k_qkv8    <<<BL_/8, 256, 0, stream>>>(src, w_in, b_in, qkv, lay);
        k_attn    <<<B_*H_, 256, 0, stream>>>(qkv, neg, attn_o);
        k_oproj_ln<<<BL_,   128, 0, stream>>>(attn_o, w_out, b_out, ln1_s, ln1_b, src, srcb, lay);
        mfma_gemm<false><<<dim3(32, 8), 512, 0, stream>>>(
            srcb, wff1t + (size_t)lay*1024*128, b_ff1 + lay*DFF_,
            nullptr, nullptr, ffh, 128);
        k_ff2_mfma<<<dim3(32, 8), 256, 0, stream>>>(
            ffh, wff2t + (size_t)lay*96*1024, ffpart);
        k_ff2ln_red<<<BL_, 128, 0, stream>>>(ffpart, b_ff2, ln2_s, ln2_b, src, lay);
    }

    k_vis_gemm  <<<dim3(8, VKS), 256, 0, stream>>>(src, w0, vparts);
    k_vis_reduce<<<32, 256, 0, stream>>>(vparts, visp);

    dim3 mg(T_/64, DFF_/128);   // (32, 8)
    mfma_gemm<true ><<<mg, 512, 0, stream>>>(grdb, w0t, b0, visp, tbi, hab, LM_);
    mfma_gemm<false><<<mg, 512, 0, stream>>>(hab,  w1t, b1, nullptr, nullptr, hbb, DFF_);
    mfma_gemm<false><<<mg, 512, 0, stream>>>(hbb,  w2t, b2, nullptr, nullptr, hab, DFF_);
    mfma_gemm<false><<<mg, 512, 0, stream>>>(hab,  w3t, b3, nullptr, nullptr, hbb, DFF_);

    k_final<<<T_, 64, 0, stream>>>(hbb, w4, b4, (float*)d_out);
}

// Round 5
// 420.016 us; speedup vs baseline: 2.2235x; 1.0494x over previous
//
#include <hip/hip_runtime.h>
#include <hip/hip_bf16.h>

#define B_ 8
#define L_ 256
#define T_ 2048
#define LM_ 4096
#define DFF_ 1024
#define D_ 84
#define H_ 4
#define HD_ 21
#define BL_ (B_*L_)          // 2048
#define VISF_ (L_*D_)        // 21504
#define VKS 16
#define VCHUNK (VISF_/VKS)   // 1344

typedef __attribute__((ext_vector_type(8))) short bf16x8;
typedef __attribute__((ext_vector_type(4))) float f32x4;

typedef const __attribute__((address_space(1))) int* gas_p;
typedef __attribute__((address_space(3))) int* las_p;
__device__ __forceinline__ void gld_lds16(const void* g, void* l) {
    __builtin_amdgcn_global_load_lds((gas_p)g, (las_p)l, 16, 0, 0);
}

// ---------------- Stage A: build src + pad bias ----------------
__global__ void k_build_src(const float* __restrict__ vf, const float* __restrict__ gB,
                            const float* __restrict__ cemb, float* __restrict__ src,
                            float* __restrict__ neg)
{
    int row = blockIdx.x * blockDim.x + threadIdx.x;
    if (row >= BL_) return;
    float v[7];
    bool allz = true;
    #pragma unroll
    for (int c = 0; c < 7; ++c) { v[c] = vf[row*7 + c]; allz = allz && (v[c] == 0.0f); }
    neg[row] = allz ? -1e9f : 0.0f;
    float* s = src + (size_t)row * D_;
    const float TWO_PI = 6.28318530717958647692f;
    #pragma unroll
    for (int d = 0; d < 5; ++d) {
        float pmin = TWO_PI * (v[0]*gB[d] + v[1]*gB[5+d] + v[2]*gB[10+d]);
        float pmax = TWO_PI * (v[3]*gB[d] + v[4]*gB[5+d] + v[5]*gB[10+d]);
        s[d]      = sinf(pmin);  s[5+d]  = cosf(pmin);
        s[10+d]   = sinf(pmax);  s[15+d] = cosf(pmax);
    }
    int cls = (int)v[6];
    const float4* ce = reinterpret_cast<const float4*>(cemb + (size_t)cls*64);
    float4* so = reinterpret_cast<float4*>(s + 20);
    #pragma unroll
    for (int i = 0; i < 16; ++i) so[i] = ce[i];
}

// ---------------- Stage B: encoder ----------------
__global__ __launch_bounds__(256) void k_qkv8(const float* __restrict__ src,
        const float* __restrict__ w_in, const float* __restrict__ b_in,
        float* __restrict__ qkv, int lay)
{
    __shared__ float s8[8][D_];
    int r0 = blockIdx.x * 8, tid = threadIdx.x;
    for (int idx = tid; idx < 8*D_; idx += 256) {
        int r = idx / D_, d = idx - r*D_;
        s8[r][d] = src[(size_t)(r0+r)*D_ + d];
    }
    __syncthreads();
    if (tid < 3*D_) {
        const float* w = w_in + (size_t)lay*D_*3*D_ + tid;
        float acc[8] = {};
        for (int d = 0; d < D_; ++d) {
            float wv = w[(size_t)d*3*D_];
            #pragma unroll
            for (int r = 0; r < 8; ++r) acc[r] = fmaf(s8[r][d], wv, acc[r]);
        }
        float bv = b_in[lay*3*D_ + tid];
        #pragma unroll
        for (int r = 0; r < 8; ++r) qkv[(size_t)(r0+r)*(3*D_) + tid] = acc[r] + bv;
    }
}

__global__ __launch_bounds__(256) void k_attn(const float* __restrict__ qkv,
        const float* __restrict__ neg, float* __restrict__ attn_o)
{
    __shared__ float ks[L_*HD_], vs[L_*HD_], ns[L_];
    int b = blockIdx.x >> 2, h = blockIdx.x & 3;
    int tid = threadIdx.x;
    for (int idx = tid; idx < L_*HD_; idx += 256) {
        int l = idx / HD_, d = idx - l*HD_;
        size_t base = ((size_t)(b*L_ + l))*(3*D_) + h*HD_ + d;
        ks[idx] = qkv[base + D_];
        vs[idx] = qkv[base + 2*D_];
    }
    if (tid < L_) ns[tid] = neg[b*L_ + tid];
    __syncthreads();
    float q[HD_];
    {
        size_t base = ((size_t)(b*L_ + tid))*(3*D_) + h*HD_;
        #pragma unroll
        for (int d = 0; d < HD_; ++d) q[d] = qkv[base + d];
    }
    const float scale = 0.21821789023599239f;  // 1/sqrt(21)
    float m_run = -INFINITY, l_run = 0.0f;
    float o[HD_];
    #pragma unroll
    for (int d = 0; d < HD_; ++d) o[d] = 0.0f;
    for (int m = 0; m < L_; ++m) {
        const float* krow = &ks[m*HD_];
        float sdot = 0.0f;
        #pragma unroll
        for (int d = 0; d < HD_; ++d) sdot = fmaf(q[d], krow[d], sdot);
        float sc = sdot * scale + ns[m];
        float nm = fmaxf(m_run, sc);
        float c = __expf(m_run - nm);
        float p = __expf(sc - nm);
        l_run = l_run * c + p;
        const float* vrow = &vs[m*HD_];
        #pragma unroll
        for (int d = 0; d < HD_; ++d) o[d] = fmaf(p, vrow[d], o[d]*c);
        m_run = nm;
    }
    float inv = 1.0f / l_run;
    float* op = attn_o + ((size_t)(b*L_ + tid))*D_ + h*HD_;
    #pragma unroll
    for (int d = 0; d < HD_; ++d) op[d] = o[d]*inv;
}

// out-proj + residual + LN; also emits bf16 K-padded src for FF1 MFMA
__global__ __launch_bounds__(128) void k_oproj_ln(const float* __restrict__ attn_o,
        const float* __restrict__ w_out, const float* __restrict__ b_out,
        const float* __restrict__ ln_s, const float* __restrict__ ln_b,
        float* __restrict__ src, __hip_bfloat16* __restrict__ srcb, int lay)
{
    __shared__ float os[D_];
    __shared__ float r1[128], r2[128];
    int row = blockIdx.x, tid = threadIdx.x;
    if (tid < D_) os[tid] = attn_o[(size_t)row*D_ + tid];
    __syncthreads();
    float y = 0.0f;
    if (tid < D_) {
        const float* w = w_out + (size_t)lay*D_*D_ + tid;
        float acc = b_out[lay*D_ + tid];
        for (int d = 0; d < D_; ++d) acc = fmaf(os[d], w[(size_t)d*D_], acc);
        y = src[(size_t)row*D_ + tid] + acc;
    }
    r1[tid] = (tid < D_) ? y : 0.0f;
    r2[tid] = (tid < D_) ? y*y : 0.0f;
    __syncthreads();
    for (int s = 64; s > 0; s >>= 1) {
        if (tid < s) { r1[tid] += r1[tid+s]; r2[tid] += r2[tid+s]; }
        __syncthreads();
    }
    float mean = r1[0] * (1.0f/D_);
    float var  = r2[0] * (1.0f/D_) - mean*mean;
    float rstd = rsqrtf(var + 1e-5f);
    float out = 0.0f;
    if (tid < D_) {
        out = (y - mean)*rstd*ln_s[lay*D_+tid] + ln_b[lay*D_+tid];
        src[(size_t)row*D_ + tid] = out;
    }
    srcb[(size_t)row*128 + tid] = (tid < D_) ? __float2bfloat16(out)
                                             : __float2bfloat16(0.0f);
}

// FF2 split-K MFMA: part[sp][2048][96] = hb[2048][1024]_slice @ wff2t[96][1024]^T
__global__ __launch_bounds__(256) void k_ff2_mfma(
        const __hip_bfloat16* __restrict__ hb,     // [2048][1024]
        const __hip_bfloat16* __restrict__ wt,     // [96][1024]
        float* __restrict__ part)                  // [8][2048][96]
{
    __shared__ __align__(16) __hip_bfloat16 sA[2][4096];   // 64m x 64k
    __shared__ __align__(16) __hip_bfloat16 sB[2][6144];   // 96n x 64k
    int tid = threadIdx.x;
    int bm = blockIdx.x * 64, sp = blockIdx.y;
    int wave = tid >> 6, lane = tid & 63;
    int wr = wave >> 1, wc = wave & 1;          // 2x2 waves: 32m x 48n each
    int l15 = lane & 15, l4 = lane >> 4;
    f32x4 acc[2][3] = {};

    const int a_m0 = tid & 63;
    const int b_i0 = tid,       b_kb0 = b_i0/96, b_n0 = b_i0%96;
    const int b_i1 = tid + 256, b_kb1 = b_i1/96, b_n1 = b_i1%96;
    const int b_i2 = tid + 512, b_kb2 = b_i2/96, b_n2 = b_i2%96;
    const __hip_bfloat16* Ap0 = hb + (size_t)(bm + a_m0)*1024 + sp*128 + (tid>>6)*8;
    const __hip_bfloat16* Ap1 = Ap0 + 32;
    const __hip_bfloat16* Bp0 = wt + (size_t)b_n0*1024 + sp*128 + b_kb0*8;
    const __hip_bfloat16* Bp1 = wt + (size_t)b_n1*1024 + sp*128 + b_kb1*8;
    const __hip_bfloat16* Bp2 = wt + (size_t)b_n2*1024 + sp*128 + b_kb2*8;

    gld_lds16(Ap0, (char*)&sA[0][0] + tid*16);
    gld_lds16(Ap1, (char*)&sA[0][0] + (tid+256)*16);
    gld_lds16(Bp0, (char*)&sB[0][0] + b_i0*16);
    gld_lds16(Bp1, (char*)&sB[0][0] + b_i1*16);
    gld_lds16(Bp2, (char*)&sB[0][0] + b_i2*16);
    #pragma unroll
    for (int t = 0; t < 2; ++t) {
        __syncthreads();
        if (t == 0) {
            gld_lds16(Ap0 + 64, (char*)&sA[1][0] + tid*16);
            gld_lds16(Ap1 + 64, (char*)&sA[1][0] + (tid+256)*16);
            gld_lds16(Bp0 + 64, (char*)&sB[1][0] + b_i0*16);
            gld_lds16(Bp1 + 64, (char*)&sB[1][0] + b_i1*16);
            gld_lds16(Bp2 + 64, (char*)&sB[1][0] + b_i2*16);
        }
        const __hip_bfloat16* sa = &sA[t][0];
        const __hip_bfloat16* sb = &sB[t][0];
        #pragma unroll
        for (int ks = 0; ks < 2; ++ks) {
            bf16x8 af[2], bfr[3];
            #pragma unroll
            for (int mi = 0; mi < 2; ++mi)
                af[mi] = *reinterpret_cast<const bf16x8*>(
                    &sa[(size_t)((ks*4 + l4)*64 + wr*32 + mi*16 + l15) * 8]);
            #pragma unroll
            for (int ni = 0; ni < 3; ++ni)
                bfr[ni] = *reinterpret_cast<const bf16x8*>(
                    &sb[(size_t)((ks*4 + l4)*96 + wc*48 + ni*16 + l15) * 8]);
            #pragma unroll
            for (int mi = 0; mi < 2; ++mi)
                #pragma unroll
                for (int ni = 0; ni < 3; ++ni)
                    acc[mi][ni] = __builtin_amdgcn_mfma_f32_16x16x32_bf16(
                        af[mi], bfr[ni], acc[mi][ni], 0, 0, 0);
        }
    }
    float* po = part + (size_t)sp*(2048*96);
    #pragma unroll
    for (int mi = 0; mi < 2; ++mi)
        #pragma unroll
        for (int reg = 0; reg < 4; ++reg) {
            int row = bm + wr*32 + mi*16 + l4*4 + reg;
            #pragma unroll
            for (int ni = 0; ni < 3; ++ni) {
                int col = wc*48 + ni*16 + l15;
                po[(size_t)row*96 + col] = acc[mi][ni][reg];
            }
        }
}

// reduce split-K partials + bias + residual + LN (over the true 84 cols)
__global__ __launch_bounds__(128) void k_ff2ln_red(const float* __restrict__ part,
        const float* __restrict__ b_ff2, const float* __restrict__ ln_s,
        const float* __restrict__ ln_b, float* __restrict__ src, int lay)
{
    __shared__ float r1[128], r2[128];
    int row = blockIdx.x, tid = threadIdx.x;
    float y = 0.0f;
    if (tid < D_) {
        #pragma unroll
        for (int sp = 0; sp < 8; ++sp)
            y += part[(size_t)sp*(2048*96) + (size_t)row*96 + tid];
        y += b_ff2[lay*D_ + tid] + src[(size_t)row*D_ + tid];
    }
    r1[tid] = (tid < D_) ? y : 0.0f;
    r2[tid] = (tid < D_) ? y*y : 0.0f;
    __syncthreads();
    for (int s = 64; s > 0; s >>= 1) {
        if (tid < s) { r1[tid] += r1[tid+s]; r2[tid] += r2[tid+s]; }
        __syncthreads();
    }
    float mean = r1[0] * (1.0f/D_);
    float var  = r2[0] * (1.0f/D_) - mean*mean;
    float rstd = rsqrtf(var + 1e-5f);
    if (tid < D_)
        src[(size_t)row*D_ + tid] = (y - mean)*rstd*ln_s[lay*D_+tid] + ln_b[lay*D_+tid];
}

// ---------------- vis part (fp32, exact): 8 rows x w0_top ----------------
__global__ __launch_bounds__(256) void k_vis_gemm(const float* __restrict__ src,
        const float* __restrict__ w0, float* __restrict__ partials)
{
    __shared__ float vf[8*VCHUNK];   // 43 KB
    int nt = blockIdx.x, sp = blockIdx.y, tid = threadIdx.x;
    int k0 = sp * VCHUNK;
    for (int idx = tid; idx < 8*VCHUNK; idx += 256) {
        int r = idx / VCHUNK, c = idx - r*VCHUNK;
        vf[idx] = src[(size_t)r*VISF_ + k0 + c];
    }
    __syncthreads();
    int n = nt*128 + (tid & 127);
    int kh = tid >> 7;
    float acc[8] = {};
    const float* wp = w0 + (size_t)(k0 + kh*(VCHUNK/2))*DFF_ + n;
    const float* vp = vf + kh*(VCHUNK/2);
    for (int kk = 0; kk < VCHUNK/2; ++kk) {
        float w = wp[(size_t)kk*DFF_];
        #pragma unroll
        for (int m = 0; m < 8; ++m) acc[m] = fmaf(vp[m*VCHUNK + kk], w, acc[m]);
    }
    __syncthreads();
    float* red = vf;  // reuse LDS
    #pragma unroll
    for (int m = 0; m < 8; ++m) red[m*256 + tid] = acc[m];
    __syncthreads();
    if (kh == 0) {
        #pragma unroll
        for (int m = 0; m < 8; ++m)
            partials[(size_t)sp*(8*DFF_) + m*DFF_ + n] = red[m*256 + tid] + red[m*256 + tid + 128];
    }
}

__global__ void k_vis_reduce(const float* __restrict__ partials, float* __restrict__ vis)
{
    int o = blockIdx.x*256 + threadIdx.x;   // < 8192
    float s = 0.0f;
    for (int sp = 0; sp < VKS; ++sp) s += partials[(size_t)sp*8192 + o];
    vis[o] = s;
}

// ---------------- bf16 conversion helpers ----------------
struct bh4 { __hip_bfloat16 x, y, z, w; };

__global__ __launch_bounds__(256) void k_f2b(const float* __restrict__ in,
        __hip_bfloat16* __restrict__ out, int n4)
{
    int i = blockIdx.x*256 + threadIdx.x;
    if (i >= n4) return;
    float4 v = reinterpret_cast<const float4*>(in)[i];
    bh4 o = { __float2bfloat16(v.x), __float2bfloat16(v.y),
              __float2bfloat16(v.z), __float2bfloat16(v.w) };
    reinterpret_cast<bh4*>(out)[i] = o;
}

// transpose+convert: W[K][N] fp32 -> WT[N][K] bf16 (exact multiples of 32)
__global__ __launch_bounds__(256) void k_wT(const float* __restrict__ W,
        __hip_bfloat16* __restrict__ WT, int K, int N)
{
    __shared__ float t[32][33];
    int kb = blockIdx.x*32, nb = blockIdx.y*32;
    int tx = threadIdx.x & 31, ty = threadIdx.x >> 5;   // ty 0..7
    #pragma unroll
    for (int i = 0; i < 4; ++i)
        t[ty + i*8][tx] = W[(size_t)(kb + ty + i*8)*N + nb + tx];
    __syncthreads();
    #pragma unroll
    for (int i = 0; i < 4; ++i)
        WT[(size_t)(nb + ty + i*8)*K + kb + tx] = __float2bfloat16(t[tx][ty + i*8]);
}

// padded transpose+convert: W[K][N] fp32 -> WT[NP][KP] bf16, zero-filled
__global__ __launch_bounds__(256) void k_wTp(const float* __restrict__ W,
        __hip_bfloat16* __restrict__ WT, int K, int N, int KP)
{
    __shared__ float t[32][33];
    int kb = blockIdx.x*32, nb = blockIdx.y*32;
    int tx = threadIdx.x & 31, ty = threadIdx.x >> 5;
    #pragma unroll
    for (int i = 0; i < 4; ++i) {
        int k = kb + ty + i*8, n = nb + tx;
        t[ty + i*8][tx] = (k < K && n < N) ? W[(size_t)k*N + n] : 0.0f;
    }
    __syncthreads();
    #pragma unroll
    for (int i = 0; i < 4; ++i)
        WT[(size_t)(nb + ty + i*8)*KP + kb + tx] = __float2bfloat16(t[tx][ty + i*8]);
}

// ---------------- MFMA GEMM: 64x64 tile, depth-2 prefetch, counted vmcnt ----------------
// C[M][N=1024] = relu(A[M][K]_bf16 @ WT[N][K]_bf16^T + bias (+ vis[bidx[m]]))
// 256 thr (4 waves, 2x2), 3 LDS buffers; stage t+2 then s_waitcnt vmcnt(8)
// (tile t's 4 loads drained, 8 stay in flight) + raw s_barrier. Grid 2 blocks/CU.
template<bool ADD_VIS>
__global__ __launch_bounds__(256) void mfma_gemm(
        const __hip_bfloat16* __restrict__ A,   // [M][K]
        const __hip_bfloat16* __restrict__ WT,  // [N][K]
        const float* __restrict__ bias,         // [N]
        const float* __restrict__ vis,          // [8][1024]
        const int* __restrict__ bidx,           // [M]
        __hip_bfloat16* __restrict__ C,         // [M][N]
        int K)
{
    constexpr int N = 1024;
    __shared__ __align__(16) __hip_bfloat16 sA[3][4096];   // 3 x 8 KB
    __shared__ __align__(16) __hip_bfloat16 sB[3][4096];   // 3 x 8 KB
    int tid = threadIdx.x;
    int bm = blockIdx.x * 64, bn = blockIdx.y * 64;
    int wave = tid >> 6, lane = tid & 63;
    int wr = wave >> 1, wc = wave & 1;          // 2x2 wave grid, 32x32 each
    int l15 = lane & 15, l4 = lane >> 4;
    f32x4 acc[2][2] = {};

    // staging coords: idx=tid -> (kb=tid>>6, r=tid&63); idx=tid+256 -> kb+4, same r
    const __hip_bfloat16* Ap = A  + (size_t)(bm + (tid & 63))*K + (tid >> 6)*8;
    const __hip_bfloat16* Bp = WT + (size_t)(bn + (tid & 63))*K + (tid >> 6)*8;

    int nsteps = K >> 6;
    auto STAGE = [&](int t, int b) {
        int ko = t << 6;
        char* la = (char*)&sA[b][0];
        char* lb = (char*)&sB[b][0];
        gld_lds16(Ap + ko,      la + tid*16);
        gld_lds16(Ap + ko + 32, la + (tid+256)*16);
        gld_lds16(Bp + ko,      lb + tid*16);
        gld_lds16(Bp + ko + 32, lb + (tid+256)*16);
    };
    STAGE(0, 0);
    if (nsteps > 1) STAGE(1, 1);

    for (int t = 0; t < nsteps; ++t) {
        if (t + 2 < nsteps) {
            STAGE(t + 2, (t + 2) % 3);
            asm volatile("s_waitcnt vmcnt(8)" ::: "memory");
        } else if (t + 1 < nsteps) {
            asm volatile("s_waitcnt vmcnt(4)" ::: "memory");
        } else {
            asm volatile("s_waitcnt vmcnt(0)" ::: "memory");
        }
        __builtin_amdgcn_s_barrier();   // tile t resident for all waves
        const __hip_bfloat16* sa = &sA[t % 3][0];
        const __hip_bfloat16* sb = &sB[t % 3][0];
        #pragma unroll
        for (int ks = 0; ks < 2; ++ks) {
            bf16x8 af[2], bfr[2];
            #pragma unroll
            for (int mi = 0; mi < 2; ++mi)
                af[mi] = *reinterpret_cast<const bf16x8*>(
                    &sa[(size_t)((ks*4 + l4)*64 + wr*32 + mi*16 + l15) * 8]);
            #pragma unroll
            for (int ni = 0; ni < 2; ++ni)
                bfr[ni] = *reinterpret_cast<const bf16x8*>(
                    &sb[(size_t)((ks*4 + l4)*64 + wc*32 + ni*16 + l15) * 8]);
            #pragma unroll
            for (int mi = 0; mi < 2; ++mi)
                #pragma unroll
                for (int ni = 0; ni < 2; ++ni)
                    acc[mi][ni] = __builtin_amdgcn_mfma_f32_16x16x32_bf16(
                        af[mi], bfr[ni], acc[mi][ni], 0, 0, 0);
        }
        __builtin_amdgcn_s_barrier();   // all waves done reading buf t%3
    }

    #pragma unroll
    for (int mi = 0; mi < 2; ++mi) {
        #pragma unroll
        for (int reg = 0; reg < 4; ++reg) {
            int row = bm + wr*32 + mi*16 + l4*4 + reg;
            const float* vrow = nullptr;
            if (ADD_VIS) vrow = vis + (size_t)bidx[row]*1024;
            #pragma unroll
            for (int ni = 0; ni < 2; ++ni) {
                int col = bn + wc*32 + ni*16 + l15;
                float v = acc[mi][ni][reg] + bias[col];
                if (ADD_VIS) v += vrow[col];
                v = fmaxf(v, 0.0f);
                C[(size_t)row*N + col] = __float2bfloat16(v);
            }
        }
    }
}

// final 1024 -> 6 (bf16 h)
__global__ __launch_bounds__(64) void k_final(const __hip_bfloat16* __restrict__ h,
        const float* __restrict__ w4, const float* __restrict__ b4, float* __restrict__ out)
{
    int t = blockIdx.x, lane = threadIdx.x;
    float acc[6] = {};
    for (int k = lane; k < DFF_; k += 64) {
        float hv = __bfloat162float(h[(size_t)t*DFF_ + k]);
        #pragma unroll
        for (int j = 0; j < 6; ++j) acc[j] = fmaf(hv, w4[k*6 + j], acc[j]);
    }
    #pragma unroll
    for (int j = 0; j < 6; ++j)
        #pragma unroll
        for (int s = 32; s > 0; s >>= 1) acc[j] += __shfl_down(acc[j], s);
    if (lane == 0) {
        #pragma unroll
        for (int j = 0; j < 6; ++j) out[(size_t)t*6 + j] = acc[j] + b4[j];
    }
}

extern "C" void kernel_launch(void* const* d_in, const int* in_sizes, int n_in,
                              void* d_out, int out_size, void* d_ws, size_t ws_size,
                              hipStream_t stream)
{
    const float* grd   = (const float*)d_in[0];
    const float* vfeat = (const float*)d_in[1];
    const int*   tbi   = (const int*)  d_in[2];
    const float* gB    = (const float*)d_in[3];
    const float* cemb  = (const float*)d_in[4];
    const float* w_in  = (const float*)d_in[5];
    const float* b_in  = (const float*)d_in[6];
    const float* w_out = (const float*)d_in[7];
    const float* b_out = (const float*)d_in[8];
    const float* ln1_s = (const float*)d_in[9];
    const float* ln1_b = (const float*)d_in[10];
    const float* w_ff1 = (const float*)d_in[11];
    const float* b_ff1 = (const float*)d_in[12];
    const float* w_ff2 = (const float*)d_in[13];
    const float* b_ff2 = (const float*)d_in[14];
    const float* ln2_s = (const float*)d_in[15];
    const float* ln2_b = (const float*)d_in[16];
    const float* w0    = (const float*)d_in[17];
    const float* b0    = (const float*)d_in[18];
    const float* w1    = (const float*)d_in[19];
    const float* b1    = (const float*)d_in[20];
    const float* w2    = (const float*)d_in[21];
    const float* b2    = (const float*)d_in[22];
    const float* w3    = (const float*)d_in[23];
    const float* b3    = (const float*)d_in[24];
    const float* w4    = (const float*)d_in[25];
    const float* b4    = (const float*)d_in[26];

    float* ws = (float*)d_ws;
    float* src    = ws;                       // 172032
    float* neg    = src    + 172032;          // 2048
    float* qkv    = neg    + 2048;            // 516096
    float* attn_o = qkv    + 516096;          // 172032
    float* vparts = attn_o + 172032;          // 131072
    float* visp   = vparts + 131072;          // 8192
    float* ffpart = visp   + 8192;            // 8*2048*96 = 1572864
    float* fend   = ffpart + 1572864;
    __hip_bfloat16* grdb  = (__hip_bfloat16*)fend;       // 8388608
    __hip_bfloat16* w0t   = grdb  + 8388608;             // 4194304
    __hip_bfloat16* w1t   = w0t   + 4194304;             // 1048576
    __hip_bfloat16* w2t   = w1t   + 1048576;             // 1048576
    __hip_bfloat16* w3t   = w2t   + 1048576;             // 1048576
    __hip_bfloat16* hab   = w3t   + 1048576;             // 2097152
    __hip_bfloat16* hbb   = hab   + 2097152;             // 2097152
    __hip_bfloat16* srcb  = hbb   + 2097152;             // 2048*128 = 262144
    __hip_bfloat16* wff1t = srcb  + 262144;              // 2*1024*128 = 262144
    __hip_bfloat16* wff2t = wff1t + 262144;              // 2*96*1024 = 196608
    __hip_bfloat16* ffh   = hab;  // alias: hab unused until head GEMMs

    // conversions (independent of encoder; issue first)
    k_f2b<<<(T_*LM_/4 + 255)/256, 256, 0, stream>>>(grd, grdb, T_*LM_/4);
    k_wT<<<dim3(LM_/32,  DFF_/32), 256, 0, stream>>>(w0 + (size_t)VISF_*DFF_, w0t, LM_,  DFF_);
    k_wT<<<dim3(DFF_/32, DFF_/32), 256, 0, stream>>>(w1, w1t, DFF_, DFF_);
    k_wT<<<dim3(DFF_/32, DFF_/32), 256, 0, stream>>>(w2, w2t, DFF_, DFF_);
    k_wT<<<dim3(DFF_/32, DFF_/32), 256, 0, stream>>>(w3, w3t, DFF_, DFF_);
    for (int l = 0; l < 2; ++l) {
        k_wTp<<<dim3(128/32, 1024/32), 256, 0, stream>>>(
            w_ff1 + (size_t)l*D_*DFF_, wff1t + (size_t)l*1024*128, D_, DFF_, 128);
        k_wTp<<<dim3(1024/32, 96/32),  256, 0, stream>>>(
            w_ff2 + (size_t)l*DFF_*D_, wff2t + (size_t)l*96*1024, DFF_, D_, 1024);
    }

    k_build_src<<<8, 256, 0, stream>>>(vfeat, gB, cemb, src, neg);

    for (int lay = 0; lay < 2; ++lay) {
        k_qkv8    <<<BL_/8, 256, 0, stream>>>(src, w_in, b_in, qkv, lay);
        k_attn    <<<B_*H_, 256, 0, stream>>>(qkv, neg, attn_o);
        k_oproj_ln<<<BL_,   128, 0, stream>>>(attn_o, w_out, b_out, ln1_s, ln1_b, src, srcb, lay);
        mfma_gemm<false><<<dim3(32, 16), 256, 0, stream>>>(
            srcb, wff1t + (size_t)lay*1024*128, b_ff1 + lay*DFF_,
            nullptr, nullptr, ffh, 128);
        k_ff2_mfma<<<dim3(32, 8), 256, 0, stream>>>(
            ffh, wff2t + (size_t)lay*96*1024, ffpart);
        k_ff2ln_red<<<BL_, 128, 0, stream>>>(ffpart, b_ff2, ln2_s, ln2_b, src, lay);
    }

    k_vis_gemm  <<<dim3(8, VKS), 256, 0, stream>>>(src, w0, vparts);
    k_vis_reduce<<<32, 256, 0, stream>>>(vparts, visp);

    dim3 mg(T_/64, DFF_/64);   // (32, 16) = 512 blocks, 2 blocks/CU
    mfma_gemm<true ><<<mg, 256, 0, stream>>>(grdb, w0t, b0, visp, tbi, hab, LM_);
    mfma_gemm<false><<<mg, 256, 0, stream>>>(hab,  w1t, b1, nullptr, nullptr, hbb, DFF_);
    mfma_gemm<false><<<mg, 256, 0, stream>>>(hbb,  w2t, b2, nullptr, nullptr, hab, DFF_);
    mfma_gemm<false><<<mg, 256, 0, stream>>>(hab,  w3t, b3, nullptr, nullptr, hbb, DFF_);

    k_final<<<T_, 64, 0, stream>>>(hbb, w4, b4, (float*)d_out);
}

// Round 6
// 314.103 us; speedup vs baseline: 2.9733x; 1.3372x over previous
//
#include <hip/hip_runtime.h>
#include <hip/hip_bf16.h>

#define B_ 8
#define L_ 256
#define T_ 2048
#define LM_ 4096
#define DFF_ 1024
#define D_ 84
#define H_ 4
#define HD_ 21
#define BL_ (B_*L_)          // 2048
#define VISF_ (L_*D_)        // 21504
#define VKS 16
#define VCHUNK (VISF_/VKS)   // 1344
#define AKS 8
#define AKEYS (L_/AKS)       // 32

typedef __attribute__((ext_vector_type(8))) short bf16x8;
typedef __attribute__((ext_vector_type(4))) float f32x4;

typedef const __attribute__((address_space(1))) int* gas_p;
typedef __attribute__((address_space(3))) int* las_p;
__device__ __forceinline__ void gld_lds16(const void* g, void* l) {
    __builtin_amdgcn_global_load_lds((gas_p)g, (las_p)l, 16, 0, 0);
}

// ---------------- Stage A: build src + pad bias ----------------
__global__ void k_build_src(const float* __restrict__ vf, const float* __restrict__ gB,
                            const float* __restrict__ cemb, float* __restrict__ src,
                            float* __restrict__ neg)
{
    int row = blockIdx.x * blockDim.x + threadIdx.x;
    if (row >= BL_) return;
    float v[7];
    bool allz = true;
    #pragma unroll
    for (int c = 0; c < 7; ++c) { v[c] = vf[row*7 + c]; allz = allz && (v[c] == 0.0f); }
    neg[row] = allz ? -1e9f : 0.0f;
    float* s = src + (size_t)row * D_;
    const float TWO_PI = 6.28318530717958647692f;
    #pragma unroll
    for (int d = 0; d < 5; ++d) {
        float pmin = TWO_PI * (v[0]*gB[d] + v[1]*gB[5+d] + v[2]*gB[10+d]);
        float pmax = TWO_PI * (v[3]*gB[d] + v[4]*gB[5+d] + v[5]*gB[10+d]);
        s[d]      = sinf(pmin);  s[5+d]  = cosf(pmin);
        s[10+d]   = sinf(pmax);  s[15+d] = cosf(pmax);
    }
    int cls = (int)v[6];
    const float4* ce = reinterpret_cast<const float4*>(cemb + (size_t)cls*64);
    float4* so = reinterpret_cast<float4*>(s + 20);
    #pragma unroll
    for (int i = 0; i < 16; ++i) so[i] = ce[i];
}

// ---------------- Stage B: encoder ----------------
__global__ __launch_bounds__(256) void k_qkv8(const float* __restrict__ src,
        const float* __restrict__ w_in, const float* __restrict__ b_in,
        float* __restrict__ qkv, int lay)
{
    __shared__ float s8[8][D_];
    int r0 = blockIdx.x * 8, tid = threadIdx.x;
    for (int idx = tid; idx < 8*D_; idx += 256) {
        int r = idx / D_, d = idx - r*D_;
        s8[r][d] = src[(size_t)(r0+r)*D_ + d];
    }
    __syncthreads();
    if (tid < 3*D_) {
        const float* w = w_in + (size_t)lay*D_*3*D_ + tid;
        float acc[8] = {};
        for (int d = 0; d < D_; ++d) {
            float wv = w[(size_t)d*3*D_];
            #pragma unroll
            for (int r = 0; r < 8; ++r) acc[r] = fmaf(s8[r][d], wv, acc[r]);
        }
        float bv = b_in[lay*3*D_ + tid];
        #pragma unroll
        for (int r = 0; r < 8; ++r) qkv[(size_t)(r0+r)*(3*D_) + tid] = acc[r] + bv;
    }
}

// split-K attention partials: grid (B*H, AKS), one thread per query
__global__ __launch_bounds__(256) void k_attn_part(const float* __restrict__ qkv,
        const float* __restrict__ neg, float* __restrict__ part)
{
    __shared__ float ks_[AKEYS*HD_], vs_[AKEYS*HD_], ns[AKEYS];
    int bh = blockIdx.x;                 // 0..31
    int b = bh >> 2, h = bh & 3;
    int sp = blockIdx.y;                 // 0..AKS-1
    int tid = threadIdx.x;               // query index
    int k0 = sp * AKEYS;
    for (int idx = tid; idx < AKEYS*HD_; idx += 256) {
        int l = idx / HD_, d = idx - l*HD_;
        size_t base = ((size_t)(b*L_ + k0 + l))*(3*D_) + h*HD_ + d;
        ks_[idx] = qkv[base + D_];
        vs_[idx] = qkv[base + 2*D_];
    }
    if (tid < AKEYS) ns[tid] = neg[b*L_ + k0 + tid];
    __syncthreads();
    float q[HD_];
    {
        size_t base = ((size_t)(b*L_ + tid))*(3*D_) + h*HD_;
        #pragma unroll
        for (int d = 0; d < HD_; ++d) q[d] = qkv[base + d];
    }
    const float scale = 0.21821789023599239f;  // 1/sqrt(21)
    float m_run = -INFINITY, l_run = 0.0f;
    float o[HD_];
    #pragma unroll
    for (int d = 0; d < HD_; ++d) o[d] = 0.0f;
    for (int m = 0; m < AKEYS; ++m) {
        const float* krow = &ks_[m*HD_];
        float sdot = 0.0f;
        #pragma unroll
        for (int d = 0; d < HD_; ++d) sdot = fmaf(q[d], krow[d], sdot);
        float sc = sdot * scale + ns[m];
        float nm = fmaxf(m_run, sc);
        float c = __expf(m_run - nm);
        float p = __expf(sc - nm);
        l_run = l_run * c + p;
        const float* vrow = &vs_[m*HD_];
        #pragma unroll
        for (int d = 0; d < HD_; ++d) o[d] = fmaf(p, vrow[d], o[d]*c);
        m_run = nm;
    }
    float* po = part + (((size_t)bh*AKS + sp)*L_ + tid)*24;
    #pragma unroll
    for (int d = 0; d < HD_; ++d) po[d] = o[d];
    po[21] = m_run;
    po[22] = l_run;
}

// merge AKS partials per (b,h,q); write attn_o
__global__ __launch_bounds__(64) void k_attn_merge(const float* __restrict__ part,
        float* __restrict__ attn_o)
{
    int bh = blockIdx.x;
    int b = bh >> 2, h = bh & 3;
    int q = blockIdx.y*64 + threadIdx.x;
    const float* pb = part + ((size_t)bh*AKS*L_ + q)*24;
    float m_tot = -INFINITY;
    #pragma unroll
    for (int sp = 0; sp < AKS; ++sp)
        m_tot = fmaxf(m_tot, pb[(size_t)sp*L_*24 + 21]);
    float l_tot = 0.0f;
    float o[HD_];
    #pragma unroll
    for (int d = 0; d < HD_; ++d) o[d] = 0.0f;
    #pragma unroll
    for (int sp = 0; sp < AKS; ++sp) {
        const float* pp = pb + (size_t)sp*L_*24;
        float e = __expf(pp[21] - m_tot);
        l_tot = fmaf(pp[22], e, l_tot);
        #pragma unroll
        for (int d = 0; d < HD_; ++d) o[d] = fmaf(pp[d], e, o[d]);
    }
    float inv = 1.0f / l_tot;
    float* op = attn_o + ((size_t)(b*L_ + q))*D_ + h*HD_;
    #pragma unroll
    for (int d = 0; d < HD_; ++d) op[d] = o[d]*inv;
}

// out-proj + residual + LN; also emits bf16 K-padded src for FF1 MFMA
__global__ __launch_bounds__(128) void k_oproj_ln(const float* __restrict__ attn_o,
        const float* __restrict__ w_out, const float* __restrict__ b_out,
        const float* __restrict__ ln_s, const float* __restrict__ ln_b,
        float* __restrict__ src, __hip_bfloat16* __restrict__ srcb, int lay)
{
    __shared__ float os[D_];
    __shared__ float r1[128], r2[128];
    int row = blockIdx.x, tid = threadIdx.x;
    if (tid < D_) os[tid] = attn_o[(size_t)row*D_ + tid];
    __syncthreads();
    float y = 0.0f;
    if (tid < D_) {
        const float* w = w_out + (size_t)lay*D_*D_ + tid;
        float acc = b_out[lay*D_ + tid];
        for (int d = 0; d < D_; ++d) acc = fmaf(os[d], w[(size_t)d*D_], acc);
        y = src[(size_t)row*D_ + tid] + acc;
    }
    r1[tid] = (tid < D_) ? y : 0.0f;
    r2[tid] = (tid < D_) ? y*y : 0.0f;
    __syncthreads();
    for (int s = 64; s > 0; s >>= 1) {
        if (tid < s) { r1[tid] += r1[tid+s]; r2[tid] += r2[tid+s]; }
        __syncthreads();
    }
    float mean = r1[0] * (1.0f/D_);
    float var  = r2[0] * (1.0f/D_) - mean*mean;
    float rstd = rsqrtf(var + 1e-5f);
    float out = 0.0f;
    if (tid < D_) {
        out = (y - mean)*rstd*ln_s[lay*D_+tid] + ln_b[lay*D_+tid];
        src[(size_t)row*D_ + tid] = out;
    }
    srcb[(size_t)row*128 + tid] = (tid < D_) ? __float2bfloat16(out)
                                             : __float2bfloat16(0.0f);
}

// FF2 split-K MFMA: part[sp][2048][96] = hb[2048][1024]_slice @ wff2t[96][1024]^T
__global__ __launch_bounds__(256) void k_ff2_mfma(
        const __hip_bfloat16* __restrict__ hb,     // [2048][1024]
        const __hip_bfloat16* __restrict__ wt,     // [96][1024]
        float* __restrict__ part)                  // [8][2048][96]
{
    __shared__ __align__(16) __hip_bfloat16 sA[2][4096];   // 64m x 64k
    __shared__ __align__(16) __hip_bfloat16 sB[2][6144];   // 96n x 64k
    int tid = threadIdx.x;
    int bm = blockIdx.x * 64, sp = blockIdx.y;
    int wave = tid >> 6, lane = tid & 63;
    int wr = wave >> 1, wc = wave & 1;          // 2x2 waves: 32m x 48n each
    int l15 = lane & 15, l4 = lane >> 4;
    f32x4 acc[2][3] = {};

    const int a_m0 = tid & 63;
    const int b_i0 = tid,       b_kb0 = b_i0/96, b_n0 = b_i0%96;
    const int b_i1 = tid + 256, b_kb1 = b_i1/96, b_n1 = b_i1%96;
    const int b_i2 = tid + 512, b_kb2 = b_i2/96, b_n2 = b_i2%96;
    const __hip_bfloat16* Ap0 = hb + (size_t)(bm + a_m0)*1024 + sp*128 + (tid>>6)*8;
    const __hip_bfloat16* Ap1 = Ap0 + 32;
    const __hip_bfloat16* Bp0 = wt + (size_t)b_n0*1024 + sp*128 + b_kb0*8;
    const __hip_bfloat16* Bp1 = wt + (size_t)b_n1*1024 + sp*128 + b_kb1*8;
    const __hip_bfloat16* Bp2 = wt + (size_t)b_n2*1024 + sp*128 + b_kb2*8;

    gld_lds16(Ap0, (char*)&sA[0][0] + tid*16);
    gld_lds16(Ap1, (char*)&sA[0][0] + (tid+256)*16);
    gld_lds16(Bp0, (char*)&sB[0][0] + b_i0*16);
    gld_lds16(Bp1, (char*)&sB[0][0] + b_i1*16);
    gld_lds16(Bp2, (char*)&sB[0][0] + b_i2*16);
    #pragma unroll
    for (int t = 0; t < 2; ++t) {
        __syncthreads();
        if (t == 0) {
            gld_lds16(Ap0 + 64, (char*)&sA[1][0] + tid*16);
            gld_lds16(Ap1 + 64, (char*)&sA[1][0] + (tid+256)*16);
            gld_lds16(Bp0 + 64, (char*)&sB[1][0] + b_i0*16);
            gld_lds16(Bp1 + 64, (char*)&sB[1][0] + b_i1*16);
            gld_lds16(Bp2 + 64, (char*)&sB[1][0] + b_i2*16);
        }
        const __hip_bfloat16* sa = &sA[t][0];
        const __hip_bfloat16* sb = &sB[t][0];
        #pragma unroll
        for (int ks = 0; ks < 2; ++ks) {
            bf16x8 af[2], bfr[3];
            #pragma unroll
            for (int mi = 0; mi < 2; ++mi)
                af[mi] = *reinterpret_cast<const bf16x8*>(
                    &sa[(size_t)((ks*4 + l4)*64 + wr*32 + mi*16 + l15) * 8]);
            #pragma unroll
            for (int ni = 0; ni < 3; ++ni)
                bfr[ni] = *reinterpret_cast<const bf16x8*>(
                    &sb[(size_t)((ks*4 + l4)*96 + wc*48 + ni*16 + l15) * 8]);
            #pragma unroll
            for (int mi = 0; mi < 2; ++mi)
                #pragma unroll
                for (int ni = 0; ni < 3; ++ni)
                    acc[mi][ni] = __builtin_amdgcn_mfma_f32_16x16x32_bf16(
                        af[mi], bfr[ni], acc[mi][ni], 0, 0, 0);
        }
    }
    float* po = part + (size_t)sp*(2048*96);
    #pragma unroll
    for (int mi = 0; mi < 2; ++mi)
        #pragma unroll
        for (int reg = 0; reg < 4; ++reg) {
            int row = bm + wr*32 + mi*16 + l4*4 + reg;
            #pragma unroll
            for (int ni = 0; ni < 3; ++ni) {
                int col = wc*48 + ni*16 + l15;
                po[(size_t)row*96 + col] = acc[mi][ni][reg];
            }
        }
}

// reduce split-K partials + bias + residual + LN (over the true 84 cols)
__global__ __launch_bounds__(128) void k_ff2ln_red(const float* __restrict__ part,
        const float* __restrict__ b_ff2, const float* __restrict__ ln_s,
        const float* __restrict__ ln_b, float* __restrict__ src, int lay)
{
    __shared__ float r1[128], r2[128];
    int row = blockIdx.x, tid = threadIdx.x;
    float y = 0.0f;
    if (tid < D_) {
        #pragma unroll
        for (int sp = 0; sp < 8; ++sp)
            y += part[(size_t)sp*(2048*96) + (size_t)row*96 + tid];
        y += b_ff2[lay*D_ + tid] + src[(size_t)row*D_ + tid];
    }
    r1[tid] = (tid < D_) ? y : 0.0f;
    r2[tid] = (tid < D_) ? y*y : 0.0f;
    __syncthreads();
    for (int s = 64; s > 0; s >>= 1) {
        if (tid < s) { r1[tid] += r1[tid+s]; r2[tid] += r2[tid+s]; }
        __syncthreads();
    }
    float mean = r1[0] * (1.0f/D_);
    float var  = r2[0] * (1.0f/D_) - mean*mean;
    float rstd = rsqrtf(var + 1e-5f);
    if (tid < D_)
        src[(size_t)row*D_ + tid] = (y - mean)*rstd*ln_s[lay*D_+tid] + ln_b[lay*D_+tid];
}

// ---------------- vis part (fp32, exact): 8 rows x w0_top ----------------
__global__ __launch_bounds__(256) void k_vis_gemm(const float* __restrict__ src,
        const float* __restrict__ w0, float* __restrict__ partials)
{
    __shared__ float vf[8*VCHUNK];   // 43 KB
    int nt = blockIdx.x, sp = blockIdx.y, tid = threadIdx.x;
    int k0 = sp * VCHUNK;
    for (int idx = tid; idx < 8*VCHUNK; idx += 256) {
        int r = idx / VCHUNK, c = idx - r*VCHUNK;
        vf[idx] = src[(size_t)r*VISF_ + k0 + c];
    }
    __syncthreads();
    int n = nt*128 + (tid & 127);
    int kh = tid >> 7;
    float acc[8] = {};
    const float* wp = w0 + (size_t)(k0 + kh*(VCHUNK/2))*DFF_ + n;
    const float* vp = vf + kh*(VCHUNK/2);
    for (int kk = 0; kk < VCHUNK/2; ++kk) {
        float w = wp[(size_t)kk*DFF_];
        #pragma unroll
        for (int m = 0; m < 8; ++m) acc[m] = fmaf(vp[m*VCHUNK + kk], w, acc[m]);
    }
    __syncthreads();
    float* red = vf;  // reuse LDS
    #pragma unroll
    for (int m = 0; m < 8; ++m) red[m*256 + tid] = acc[m];
    __syncthreads();
    if (kh == 0) {
        #pragma unroll
        for (int m = 0; m < 8; ++m)
            partials[(size_t)sp*(8*DFF_) + m*DFF_ + n] = red[m*256 + tid] + red[m*256 + tid + 128];
    }
}

__global__ void k_vis_reduce(const float* __restrict__ partials, float* __restrict__ vis)
{
    int o = blockIdx.x*256 + threadIdx.x;   // < 8192
    float s = 0.0f;
    for (int sp = 0; sp < VKS; ++sp) s += partials[(size_t)sp*8192 + o];
    vis[o] = s;
}

// ---------------- bf16 conversion helpers ----------------
struct bh4 { __hip_bfloat16 x, y, z, w; };

__global__ __launch_bounds__(256) void k_f2b(const float* __restrict__ in,
        __hip_bfloat16* __restrict__ out, int n4)
{
    int i = blockIdx.x*256 + threadIdx.x;
    if (i >= n4) return;
    float4 v = reinterpret_cast<const float4*>(in)[i];
    bh4 o = { __float2bfloat16(v.x), __float2bfloat16(v.y),
              __float2bfloat16(v.z), __float2bfloat16(v.w) };
    reinterpret_cast<bh4*>(out)[i] = o;
}

// transpose+convert: W[K][N] fp32 -> WT[N][K] bf16 (exact multiples of 32)
__global__ __launch_bounds__(256) void k_wT(const float* __restrict__ W,
        __hip_bfloat16* __restrict__ WT, int K, int N)
{
    __shared__ float t[32][33];
    int kb = blockIdx.x*32, nb = blockIdx.y*32;
    int tx = threadIdx.x & 31, ty = threadIdx.x >> 5;   // ty 0..7
    #pragma unroll
    for (int i = 0; i < 4; ++i)
        t[ty + i*8][tx] = W[(size_t)(kb + ty + i*8)*N + nb + tx];
    __syncthreads();
    #pragma unroll
    for (int i = 0; i < 4; ++i)
        WT[(size_t)(nb + ty + i*8)*K + kb + tx] = __float2bfloat16(t[tx][ty + i*8]);
}

// padded transpose+convert: W[K][N] fp32 -> WT[NP][KP] bf16, zero-filled
__global__ __launch_bounds__(256) void k_wTp(const float* __restrict__ W,
        __hip_bfloat16* __restrict__ WT, int K, int N, int KP)
{
    __shared__ float t[32][33];
    int kb = blockIdx.x*32, nb = blockIdx.y*32;
    int tx = threadIdx.x & 31, ty = threadIdx.x >> 5;
    #pragma unroll
    for (int i = 0; i < 4; ++i) {
        int k = kb + ty + i*8, n = nb + tx;
        t[ty + i*8][tx] = (k < K && n < N) ? W[(size_t)k*N + n] : 0.0f;
    }
    __syncthreads();
    #pragma unroll
    for (int i = 0; i < 4; ++i)
        WT[(size_t)(nb + ty + i*8)*KP + kb + tx] = __float2bfloat16(t[tx][ty + i*8]);
}

// ---------------- MFMA GEMM: 64x64 tile, depth-2 prefetch, counted vmcnt ----------------
template<bool ADD_VIS>
__global__ __launch_bounds__(256) void mfma_gemm(
        const __hip_bfloat16* __restrict__ A,   // [M][K]
        const __hip_bfloat16* __restrict__ WT,  // [N][K]
        const float* __restrict__ bias,         // [N]
        const float* __restrict__ vis,          // [8][1024]
        const int* __restrict__ bidx,           // [M]
        __hip_bfloat16* __restrict__ C,         // [M][N]
        int K)
{
    constexpr int N = 1024;
    __shared__ __align__(16) __hip_bfloat16 sA[3][4096];   // 3 x 8 KB
    __shared__ __align__(16) __hip_bfloat16 sB[3][4096];   // 3 x 8 KB
    int tid = threadIdx.x;
    int bm = blockIdx.x * 64, bn = blockIdx.y * 64;
    int wave = tid >> 6, lane = tid & 63;
    int wr = wave >> 1, wc = wave & 1;          // 2x2 wave grid, 32x32 each
    int l15 = lane & 15, l4 = lane >> 4;
    f32x4 acc[2][2] = {};

    const __hip_bfloat16* Ap = A  + (size_t)(bm + (tid & 63))*K + (tid >> 6)*8;
    const __hip_bfloat16* Bp = WT + (size_t)(bn + (tid & 63))*K + (tid >> 6)*8;

    int nsteps = K >> 6;
    auto STAGE = [&](int t, int b) {
        int ko = t << 6;
        char* la = (char*)&sA[b][0];
        char* lb = (char*)&sB[b][0];
        gld_lds16(Ap + ko,      la + tid*16);
        gld_lds16(Ap + ko + 32, la + (tid+256)*16);
        gld_lds16(Bp + ko,      lb + tid*16);
        gld_lds16(Bp + ko + 32, lb + (tid+256)*16);
    };
    STAGE(0, 0);
    if (nsteps > 1) STAGE(1, 1);

    for (int t = 0; t < nsteps; ++t) {
        if (t + 2 < nsteps) {
            STAGE(t + 2, (t + 2) % 3);
            asm volatile("s_waitcnt vmcnt(8)" ::: "memory");
        } else if (t + 1 < nsteps) {
            asm volatile("s_waitcnt vmcnt(4)" ::: "memory");
        } else {
            asm volatile("s_waitcnt vmcnt(0)" ::: "memory");
        }
        __builtin_amdgcn_s_barrier();   // tile t resident for all waves
        const __hip_bfloat16* sa = &sA[t % 3][0];
        const __hip_bfloat16* sb = &sB[t % 3][0];
        #pragma unroll
        for (int ks = 0; ks < 2; ++ks) {
            bf16x8 af[2], bfr[2];
            #pragma unroll
            for (int mi = 0; mi < 2; ++mi)
                af[mi] = *reinterpret_cast<const bf16x8*>(
                    &sa[(size_t)((ks*4 + l4)*64 + wr*32 + mi*16 + l15) * 8]);
            #pragma unroll
            for (int ni = 0; ni < 2; ++ni)
                bfr[ni] = *reinterpret_cast<const bf16x8*>(
                    &sb[(size_t)((ks*4 + l4)*64 + wc*32 + ni*16 + l15) * 8]);
            #pragma unroll
            for (int mi = 0; mi < 2; ++mi)
                #pragma unroll
                for (int ni = 0; ni < 2; ++ni)
                    acc[mi][ni] = __builtin_amdgcn_mfma_f32_16x16x32_bf16(
                        af[mi], bfr[ni], acc[mi][ni], 0, 0, 0);
        }
        __builtin_amdgcn_s_barrier();   // all waves done reading buf t%3
    }

    #pragma unroll
    for (int mi = 0; mi < 2; ++mi) {
        #pragma unroll
        for (int reg = 0; reg < 4; ++reg) {
            int row = bm + wr*32 + mi*16 + l4*4 + reg;
            const float* vrow = nullptr;
            if (ADD_VIS) vrow = vis + (size_t)bidx[row]*1024;
            #pragma unroll
            for (int ni = 0; ni < 2; ++ni) {
                int col = bn + wc*32 + ni*16 + l15;
                float v = acc[mi][ni][reg] + bias[col];
                if (ADD_VIS) v += vrow[col];
                v = fmaxf(v, 0.0f);
                C[(size_t)row*N + col] = __float2bfloat16(v);
            }
        }
    }
}

// final 1024 -> 6 (bf16 h)
__global__ __launch_bounds__(64) void k_final(const __hip_bfloat16* __restrict__ h,
        const float* __restrict__ w4, const float* __restrict__ b4, float* __restrict__ out)
{
    int t = blockIdx.x, lane = threadIdx.x;
    float acc[6] = {};
    for (int k = lane; k < DFF_; k += 64) {
        float hv = __bfloat162float(h[(size_t)t*DFF_ + k]);
        #pragma unroll
        for (int j = 0; j < 6; ++j) acc[j] = fmaf(hv, w4[k*6 + j], acc[j]);
    }
    #pragma unroll
    for (int j = 0; j < 6; ++j)
        #pragma unroll
        for (int s = 32; s > 0; s >>= 1) acc[j] += __shfl_down(acc[j], s);
    if (lane == 0) {
        #pragma unroll
        for (int j = 0; j < 6; ++j) out[(size_t)t*6 + j] = acc[j] + b4[j];
    }
}

extern "C" void kernel_launch(void* const* d_in, const int* in_sizes, int n_in,
                              void* d_out, int out_size, void* d_ws, size_t ws_size,
                              hipStream_t stream)
{
    const float* grd   = (const float*)d_in[0];
    const float* vfeat = (const float*)d_in[1];
    const int*   tbi   = (const int*)  d_in[2];
    const float* gB    = (const float*)d_in[3];
    const float* cemb  = (const float*)d_in[4];
    const float* w_in  = (const float*)d_in[5];
    const float* b_in  = (const float*)d_in[6];
    const float* w_out = (const float*)d_in[7];
    const float* b_out = (const float*)d_in[8];
    const float* ln1_s = (const float*)d_in[9];
    const float* ln1_b = (const float*)d_in[10];
    const float* w_ff1 = (const float*)d_in[11];
    const float* b_ff1 = (const float*)d_in[12];
    const float* w_ff2 = (const float*)d_in[13];
    const float* b_ff2 = (const float*)d_in[14];
    const float* ln2_s = (const float*)d_in[15];
    const float* ln2_b = (const float*)d_in[16];
    const float* w0    = (const float*)d_in[17];
    const float* b0    = (const float*)d_in[18];
    const float* w1    = (const float*)d_in[19];
    const float* b1    = (const float*)d_in[20];
    const float* w2    = (const float*)d_in[21];
    const float* b2    = (const float*)d_in[22];
    const float* w3    = (const float*)d_in[23];
    const float* b3    = (const float*)d_in[24];
    const float* w4    = (const float*)d_in[25];
    const float* b4    = (const float*)d_in[26];

    float* ws = (float*)d_ws;
    float* src    = ws;                       // 172032
    float* neg    = src    + 172032;          // 2048
    float* qkv    = neg    + 2048;            // 516096
    float* attn_o = qkv    + 516096;          // 172032
    float* vparts = attn_o + 172032;          // 131072
    float* visp   = vparts + 131072;          // 8192
    float* ffpart = visp   + 8192;            // 1572864 (shared: attn partials / ff2 partials)
    float* fend   = ffpart + 1572864;
    __hip_bfloat16* grdb  = (__hip_bfloat16*)fend;       // 8388608
    __hip_bfloat16* w0t   = grdb  + 8388608;             // 4194304
    __hip_bfloat16* w1t   = w0t   + 4194304;             // 1048576
    __hip_bfloat16* w2t   = w1t   + 1048576;             // 1048576
    __hip_bfloat16* w3t   = w2t   + 1048576;             // 1048576
    __hip_bfloat16* hab   = w3t   + 1048576;             // 2097152
    __hip_bfloat16* hbb   = hab   + 2097152;             // 2097152
    __hip_bfloat16* srcb  = hbb   + 2097152;             // 262144
    __hip_bfloat16* wff1t = srcb  + 262144;              // 262144
    __hip_bfloat16* wff2t = wff1t + 262144;              // 196608
    __hip_bfloat16* ffh   = hab;  // alias: hab unused until head GEMMs

    // conversions (independent of encoder; issue first)
    k_f2b<<<(T_*LM_/4 + 255)/256, 256, 0, stream>>>(grd, grdb, T_*LM_/4);
    k_wT<<<dim3(LM_/32,  DFF_/32), 256, 0, stream>>>(w0 + (size_t)VISF_*DFF_, w0t, LM_,  DFF_);
    k_wT<<<dim3(DFF_/32, DFF_/32), 256, 0, stream>>>(w1, w1t, DFF_, DFF_);
    k_wT<<<dim3(DFF_/32, DFF_/32), 256, 0, stream>>>(w2, w2t, DFF_, DFF_);
    k_wT<<<dim3(DFF_/32, DFF_/32), 256, 0, stream>>>(w3, w3t, DFF_, DFF_);
    for (int l = 0; l < 2; ++l) {
        k_wTp<<<dim3(128/32, 1024/32), 256, 0, stream>>>(
            w_ff1 + (size_t)l*D_*DFF_, wff1t + (size_t)l*1024*128, D_, DFF_, 128);
        k_wTp<<<dim3(1024/32, 96/32),  256, 0, stream>>>(
            w_ff2 + (size_t)l*DFF_*D_, wff2t + (size_t)l*96*1024, DFF_, D_, 1024);
    }

    k_build_src<<<8, 256, 0, stream>>>(vfeat, gB, cemb, src, neg);

    for (int lay = 0; lay < 2; ++lay) {
        k_qkv8      <<<BL_/8, 256, 0, stream>>>(src, w_in, b_in, qkv, lay);
        k_attn_part <<<dim3(B_*H_, AKS), 256, 0, stream>>>(qkv, neg, ffpart);
        k_attn_merge<<<dim3(B_*H_, 4), 64, 0, stream>>>(ffpart, attn_o);
        k_oproj_ln  <<<BL_, 128, 0, stream>>>(attn_o, w_out, b_out, ln1_s, ln1_b, src, srcb, lay);
        mfma_gemm<false><<<dim3(32, 16), 256, 0, stream>>>(
            srcb, wff1t + (size_t)lay*1024*128, b_ff1 + lay*DFF_,
            nullptr, nullptr, ffh, 128);
        k_ff2_mfma<<<dim3(32, 8), 256, 0, stream>>>(
            ffh, wff2t + (size_t)lay*96*1024, ffpart);
        k_ff2ln_red<<<BL_, 128, 0, stream>>>(ffpart, b_ff2, ln2_s, ln2_b, src, lay);
    }

    k_vis_gemm  <<<dim3(8, VKS), 256, 0, stream>>>(src, w0, vparts);
    k_vis_reduce<<<32, 256, 0, stream>>>(vparts, visp);

    dim3 mg(T_/64, DFF_/64);   // (32, 16) = 512 blocks, 2 blocks/CU
    mfma_gemm<true ><<<mg, 256, 0, stream>>>(grdb, w0t, b0, visp, tbi, hab, LM_);
    mfma_gemm<false><<<mg, 256, 0, stream>>>(hab,  w1t, b1, nullptr, nullptr, hbb, DFF_);
    mfma_gemm<false><<<mg, 256, 0, stream>>>(hbb,  w2t, b2, nullptr, nullptr, hab, DFF_);
    mfma_gemm<false><<<mg, 256, 0, stream>>>(hab,  w3t, b3, nullptr, nullptr, hbb, DFF_);

    k_final<<<T_, 64, 0, stream>>>(hbb, w4, b4, (float*)d_out);
}

// Round 7
// 290.300 us; speedup vs baseline: 3.2171x; 1.0820x over previous
//
#include <hip/hip_runtime.h>
#include <hip/hip_bf16.h>

#define B_ 8
#define L_ 256
#define T_ 2048
#define LM_ 4096
#define DFF_ 1024
#define D_ 84
#define H_ 4
#define HD_ 21
#define BL_ (B_*L_)          // 2048
#define VISF_ (L_*D_)        // 21504
#define VKS 168
#define VCHUNK (VISF_/VKS)   // 128
#define AKS 8
#define AKEYS (L_/AKS)       // 32

typedef __attribute__((ext_vector_type(8))) short bf16x8;
typedef __attribute__((ext_vector_type(4))) float f32x4;

typedef const __attribute__((address_space(1))) int* gas_p;
typedef __attribute__((address_space(3))) int* las_p;
__device__ __forceinline__ void gld_lds16(const void* g, void* l) {
    __builtin_amdgcn_global_load_lds((gas_p)g, (las_p)l, 16, 0, 0);
}

// ---------------- Stage A: build src + pad bias ----------------
__global__ void k_build_src(const float* __restrict__ vf, const float* __restrict__ gB,
                            const float* __restrict__ cemb, float* __restrict__ src,
                            float* __restrict__ neg)
{
    int row = blockIdx.x * blockDim.x + threadIdx.x;
    if (row >= BL_) return;
    float v[7];
    bool allz = true;
    #pragma unroll
    for (int c = 0; c < 7; ++c) { v[c] = vf[row*7 + c]; allz = allz && (v[c] == 0.0f); }
    neg[row] = allz ? -1e9f : 0.0f;
    float* s = src + (size_t)row * D_;
    const float TWO_PI = 6.28318530717958647692f;
    #pragma unroll
    for (int d = 0; d < 5; ++d) {
        float pmin = TWO_PI * (v[0]*gB[d] + v[1]*gB[5+d] + v[2]*gB[10+d]);
        float pmax = TWO_PI * (v[3]*gB[d] + v[4]*gB[5+d] + v[5]*gB[10+d]);
        s[d]      = sinf(pmin);  s[5+d]  = cosf(pmin);
        s[10+d]   = sinf(pmax);  s[15+d] = cosf(pmax);
    }
    int cls = (int)v[6];
    const float4* ce = reinterpret_cast<const float4*>(cemb + (size_t)cls*64);
    float4* so = reinterpret_cast<float4*>(s + 20);
    #pragma unroll
    for (int i = 0; i < 16; ++i) so[i] = ce[i];
}

// ---------------- Stage B: encoder ----------------
__global__ __launch_bounds__(256) void k_qkv8(const float* __restrict__ src,
        const float* __restrict__ w_in, const float* __restrict__ b_in,
        float* __restrict__ qkv, int lay)
{
    __shared__ float s8[8][D_];
    int r0 = blockIdx.x * 8, tid = threadIdx.x;
    for (int idx = tid; idx < 8*D_; idx += 256) {
        int r = idx / D_, d = idx - r*D_;
        s8[r][d] = src[(size_t)(r0+r)*D_ + d];
    }
    __syncthreads();
    if (tid < 3*D_) {
        const float* w = w_in + (size_t)lay*D_*3*D_ + tid;
        float acc[8] = {};
        for (int d = 0; d < D_; ++d) {
            float wv = w[(size_t)d*3*D_];
            #pragma unroll
            for (int r = 0; r < 8; ++r) acc[r] = fmaf(s8[r][d], wv, acc[r]);
        }
        float bv = b_in[lay*3*D_ + tid];
        #pragma unroll
        for (int r = 0; r < 8; ++r) qkv[(size_t)(r0+r)*(3*D_) + tid] = acc[r] + bv;
    }
}

// split-K attention partials: grid (B*H, AKS), one thread per query
__global__ __launch_bounds__(256) void k_attn_part(const float* __restrict__ qkv,
        const float* __restrict__ neg, float* __restrict__ part)
{
    __shared__ float ks_[AKEYS*HD_], vs_[AKEYS*HD_], ns[AKEYS];
    int bh = blockIdx.x;                 // 0..31
    int b = bh >> 2, h = bh & 3;
    int sp = blockIdx.y;                 // 0..AKS-1
    int tid = threadIdx.x;               // query index
    int k0 = sp * AKEYS;
    for (int idx = tid; idx < AKEYS*HD_; idx += 256) {
        int l = idx / HD_, d = idx - l*HD_;
        size_t base = ((size_t)(b*L_ + k0 + l))*(3*D_) + h*HD_ + d;
        ks_[idx] = qkv[base + D_];
        vs_[idx] = qkv[base + 2*D_];
    }
    if (tid < AKEYS) ns[tid] = neg[b*L_ + k0 + tid];
    __syncthreads();
    float q[HD_];
    {
        size_t base = ((size_t)(b*L_ + tid))*(3*D_) + h*HD_;
        #pragma unroll
        for (int d = 0; d < HD_; ++d) q[d] = qkv[base + d];
    }
    const float scale = 0.21821789023599239f;  // 1/sqrt(21)
    float m_run = -INFINITY, l_run = 0.0f;
    float o[HD_];
    #pragma unroll
    for (int d = 0; d < HD_; ++d) o[d] = 0.0f;
    for (int m = 0; m < AKEYS; ++m) {
        const float* krow = &ks_[m*HD_];
        float sdot = 0.0f;
        #pragma unroll
        for (int d = 0; d < HD_; ++d) sdot = fmaf(q[d], krow[d], sdot);
        float sc = sdot * scale + ns[m];
        float nm = fmaxf(m_run, sc);
        float c = __expf(m_run - nm);
        float p = __expf(sc - nm);
        l_run = l_run * c + p;
        const float* vrow = &vs_[m*HD_];
        #pragma unroll
        for (int d = 0; d < HD_; ++d) o[d] = fmaf(p, vrow[d], o[d]*c);
        m_run = nm;
    }
    float* po = part + (((size_t)bh*AKS + sp)*L_ + tid)*24;
    #pragma unroll
    for (int d = 0; d < HD_; ++d) po[d] = o[d];
    po[21] = m_run;
    po[22] = l_run;
}

// merge AKS partials per (b,h,q); write attn_o
__global__ __launch_bounds__(64) void k_attn_merge(const float* __restrict__ part,
        float* __restrict__ attn_o)
{
    int bh = blockIdx.x;
    int b = bh >> 2, h = bh & 3;
    int q = blockIdx.y*64 + threadIdx.x;
    const float* pb = part + ((size_t)bh*AKS*L_ + q)*24;
    float m_tot = -INFINITY;
    #pragma unroll
    for (int sp = 0; sp < AKS; ++sp)
        m_tot = fmaxf(m_tot, pb[(size_t)sp*L_*24 + 21]);
    float l_tot = 0.0f;
    float o[HD_];
    #pragma unroll
    for (int d = 0; d < HD_; ++d) o[d] = 0.0f;
    #pragma unroll
    for (int sp = 0; sp < AKS; ++sp) {
        const float* pp = pb + (size_t)sp*L_*24;
        float e = __expf(pp[21] - m_tot);
        l_tot = fmaf(pp[22], e, l_tot);
        #pragma unroll
        for (int d = 0; d < HD_; ++d) o[d] = fmaf(pp[d], e, o[d]);
    }
    float inv = 1.0f / l_tot;
    float* op = attn_o + ((size_t)(b*L_ + q))*D_ + h*HD_;
    #pragma unroll
    for (int d = 0; d < HD_; ++d) op[d] = o[d]*inv;
}

// out-proj + residual + LN; also emits bf16 K-padded src for FF1 MFMA
__global__ __launch_bounds__(128) void k_oproj_ln(const float* __restrict__ attn_o,
        const float* __restrict__ w_out, const float* __restrict__ b_out,
        const float* __restrict__ ln_s, const float* __restrict__ ln_b,
        float* __restrict__ src, __hip_bfloat16* __restrict__ srcb, int lay)
{
    __shared__ float os[D_];
    __shared__ float r1[128], r2[128];
    int row = blockIdx.x, tid = threadIdx.x;
    if (tid < D_) os[tid] = attn_o[(size_t)row*D_ + tid];
    __syncthreads();
    float y = 0.0f;
    if (tid < D_) {
        const float* w = w_out + (size_t)lay*D_*D_ + tid;
        float acc = b_out[lay*D_ + tid];
        for (int d = 0; d < D_; ++d) acc = fmaf(os[d], w[(size_t)d*D_], acc);
        y = src[(size_t)row*D_ + tid] + acc;
    }
    r1[tid] = (tid < D_) ? y : 0.0f;
    r2[tid] = (tid < D_) ? y*y : 0.0f;
    __syncthreads();
    for (int s = 64; s > 0; s >>= 1) {
        if (tid < s) { r1[tid] += r1[tid+s]; r2[tid] += r2[tid+s]; }
        __syncthreads();
    }
    float mean = r1[0] * (1.0f/D_);
    float var  = r2[0] * (1.0f/D_) - mean*mean;
    float rstd = rsqrtf(var + 1e-5f);
    float out = 0.0f;
    if (tid < D_) {
        out = (y - mean)*rstd*ln_s[lay*D_+tid] + ln_b[lay*D_+tid];
        src[(size_t)row*D_ + tid] = out;
    }
    srcb[(size_t)row*128 + tid] = (tid < D_) ? __float2bfloat16(out)
                                             : __float2bfloat16(0.0f);
}

// FF2 split-K MFMA: part[sp][2048][96] = hb[2048][1024]_slice @ wff2t[96][1024]^T
__global__ __launch_bounds__(256) void k_ff2_mfma(
        const __hip_bfloat16* __restrict__ hb,     // [2048][1024]
        const __hip_bfloat16* __restrict__ wt,     // [96][1024]
        float* __restrict__ part)                  // [8][2048][96]
{
    __shared__ __align__(16) __hip_bfloat16 sA[2][4096];   // 64m x 64k
    __shared__ __align__(16) __hip_bfloat16 sB[2][6144];   // 96n x 64k
    int tid = threadIdx.x;
    int bm = blockIdx.x * 64, sp = blockIdx.y;
    int wave = tid >> 6, lane = tid & 63;
    int wr = wave >> 1, wc = wave & 1;          // 2x2 waves: 32m x 48n each
    int l15 = lane & 15, l4 = lane >> 4;
    f32x4 acc[2][3] = {};

    const int a_m0 = tid & 63;
    const int b_i0 = tid,       b_kb0 = b_i0/96, b_n0 = b_i0%96;
    const int b_i1 = tid + 256, b_kb1 = b_i1/96, b_n1 = b_i1%96;
    const int b_i2 = tid + 512, b_kb2 = b_i2/96, b_n2 = b_i2%96;
    const __hip_bfloat16* Ap0 = hb + (size_t)(bm + a_m0)*1024 + sp*128 + (tid>>6)*8;
    const __hip_bfloat16* Ap1 = Ap0 + 32;
    const __hip_bfloat16* Bp0 = wt + (size_t)b_n0*1024 + sp*128 + b_kb0*8;
    const __hip_bfloat16* Bp1 = wt + (size_t)b_n1*1024 + sp*128 + b_kb1*8;
    const __hip_bfloat16* Bp2 = wt + (size_t)b_n2*1024 + sp*128 + b_kb2*8;

    gld_lds16(Ap0, (char*)&sA[0][0] + tid*16);
    gld_lds16(Ap1, (char*)&sA[0][0] + (tid+256)*16);
    gld_lds16(Bp0, (char*)&sB[0][0] + b_i0*16);
    gld_lds16(Bp1, (char*)&sB[0][0] + b_i1*16);
    gld_lds16(Bp2, (char*)&sB[0][0] + b_i2*16);
    #pragma unroll
    for (int t = 0; t < 2; ++t) {
        __syncthreads();
        if (t == 0) {
            gld_lds16(Ap0 + 64, (char*)&sA[1][0] + tid*16);
            gld_lds16(Ap1 + 64, (char*)&sA[1][0] + (tid+256)*16);
            gld_lds16(Bp0 + 64, (char*)&sB[1][0] + b_i0*16);
            gld_lds16(Bp1 + 64, (char*)&sB[1][0] + b_i1*16);
            gld_lds16(Bp2 + 64, (char*)&sB[1][0] + b_i2*16);
        }
        const __hip_bfloat16* sa = &sA[t][0];
        const __hip_bfloat16* sb = &sB[t][0];
        #pragma unroll
        for (int ks = 0; ks < 2; ++ks) {
            bf16x8 af[2], bfr[3];
            #pragma unroll
            for (int mi = 0; mi < 2; ++mi)
                af[mi] = *reinterpret_cast<const bf16x8*>(
                    &sa[(size_t)((ks*4 + l4)*64 + wr*32 + mi*16 + l15) * 8]);
            #pragma unroll
            for (int ni = 0; ni < 3; ++ni)
                bfr[ni] = *reinterpret_cast<const bf16x8*>(
                    &sb[(size_t)((ks*4 + l4)*96 + wc*48 + ni*16 + l15) * 8]);
            #pragma unroll
            for (int mi = 0; mi < 2; ++mi)
                #pragma unroll
                for (int ni = 0; ni < 3; ++ni)
                    acc[mi][ni] = __builtin_amdgcn_mfma_f32_16x16x32_bf16(
                        af[mi], bfr[ni], acc[mi][ni], 0, 0, 0);
        }
    }
    float* po = part + (size_t)sp*(2048*96);
    #pragma unroll
    for (int mi = 0; mi < 2; ++mi)
        #pragma unroll
        for (int reg = 0; reg < 4; ++reg) {
            int row = bm + wr*32 + mi*16 + l4*4 + reg;
            #pragma unroll
            for (int ni = 0; ni < 3; ++ni) {
                int col = wc*48 + ni*16 + l15;
                po[(size_t)row*96 + col] = acc[mi][ni][reg];
            }
        }
}

// reduce split-K partials + bias + residual + LN (over the true 84 cols)
__global__ __launch_bounds__(128) void k_ff2ln_red(const float* __restrict__ part,
        const float* __restrict__ b_ff2, const float* __restrict__ ln_s,
        const float* __restrict__ ln_b, float* __restrict__ src, int lay)
{
    __shared__ float r1[128], r2[128];
    int row = blockIdx.x, tid = threadIdx.x;
    float y = 0.0f;
    if (tid < D_) {
        #pragma unroll
        for (int sp = 0; sp < 8; ++sp)
            y += part[(size_t)sp*(2048*96) + (size_t)row*96 + tid];
        y += b_ff2[lay*D_ + tid] + src[(size_t)row*D_ + tid];
    }
    r1[tid] = (tid < D_) ? y : 0.0f;
    r2[tid] = (tid < D_) ? y*y : 0.0f;
    __syncthreads();
    for (int s = 64; s > 0; s >>= 1) {
        if (tid < s) { r1[tid] += r1[tid+s]; r2[tid] += r2[tid+s]; }
        __syncthreads();
    }
    float mean = r1[0] * (1.0f/D_);
    float var  = r2[0] * (1.0f/D_) - mean*mean;
    float rstd = rsqrtf(var + 1e-5f);
    if (tid < D_)
        src[(size_t)row*D_ + tid] = (y - mean)*rstd*ln_s[lay*D_+tid] + ln_b[lay*D_+tid];
}

// ---------------- vis part (fp32, exact, BW-optimized) ----------------
// grid (8 n-tiles, VKS=168 k-splits of 128); 256 thr; thread = 4 cols x 16 k's
__global__ __launch_bounds__(256) void k_vis_gemm(const float* __restrict__ src,
        const float* __restrict__ w0, float* __restrict__ partials)
{
    __shared__ float vf[8][VCHUNK];        // 4 KB
    __shared__ float red[8][256][4];       // 32 KB
    int nt = blockIdx.x, sp = blockIdx.y, tid = threadIdx.x;
    int k0 = sp * VCHUNK;
    for (int idx = tid; idx < 8*VCHUNK; idx += 256) {
        int r = idx >> 7, c = idx & 127;
        vf[r][c] = src[(size_t)r*VISF_ + k0 + c];
    }
    __syncthreads();
    int ng = tid & 31;          // 4-col group
    int kh = tid >> 5;          // 0..7, 16 k's each
    const float* wp = w0 + (size_t)(k0 + kh*16)*DFF_ + nt*128 + ng*4;
    float acc[8][4] = {};
    #pragma unroll 4
    for (int kk = 0; kk < 16; ++kk) {
        float4 w = *reinterpret_cast<const float4*>(wp + (size_t)kk*DFF_);
        #pragma unroll
        for (int m = 0; m < 8; ++m) {
            float sv = vf[m][kh*16 + kk];
            acc[m][0] = fmaf(sv, w.x, acc[m][0]);
            acc[m][1] = fmaf(sv, w.y, acc[m][1]);
            acc[m][2] = fmaf(sv, w.z, acc[m][2]);
            acc[m][3] = fmaf(sv, w.w, acc[m][3]);
        }
    }
    #pragma unroll
    for (int m = 0; m < 8; ++m)
        *reinterpret_cast<float4*>(&red[m][tid][0]) =
            make_float4(acc[m][0], acc[m][1], acc[m][2], acc[m][3]);
    __syncthreads();
    // outputs: 8m x 32ng x 4c = 1024 = 256 thr x 4
    int m2 = tid >> 5, ng2 = tid & 31;
    float4 s = *reinterpret_cast<const float4*>(&red[m2][ng2][0]);
    #pragma unroll
    for (int j = 1; j < 8; ++j) {
        float4 v = *reinterpret_cast<const float4*>(&red[m2][j*32 + ng2][0]);
        s.x += v.x; s.y += v.y; s.z += v.z; s.w += v.w;
    }
    *reinterpret_cast<float4*>(
        &partials[(size_t)sp*8192 + m2*1024 + nt*128 + ng2*4]) = s;
}

// level-1 reduce: grid (32, 12); each sums 14 of 168 splits
__global__ __launch_bounds__(256) void k_vis_red1(const float* __restrict__ partials,
        float* __restrict__ p2)
{
    int o = blockIdx.x*256 + threadIdx.x;   // < 8192
    int g = blockIdx.y;                      // 0..11
    float s = 0.0f;
    #pragma unroll
    for (int j = 0; j < 14; ++j) s += partials[(size_t)(g*14 + j)*8192 + o];
    p2[(size_t)g*8192 + o] = s;
}

// level-2 reduce: grid 32; sums 12
__global__ __launch_bounds__(256) void k_vis_red2(const float* __restrict__ p2,
        float* __restrict__ vis)
{
    int o = blockIdx.x*256 + threadIdx.x;
    float s = 0.0f;
    #pragma unroll
    for (int g = 0; g < 12; ++g) s += p2[(size_t)g*8192 + o];
    vis[o] = s;
}

// ---------------- bf16 conversion helpers ----------------
struct bh4 { __hip_bfloat16 x, y, z, w; };

__global__ __launch_bounds__(256) void k_f2b(const float* __restrict__ in,
        __hip_bfloat16* __restrict__ out, int n4)
{
    int i = blockIdx.x*256 + threadIdx.x;
    if (i >= n4) return;
    float4 v = reinterpret_cast<const float4*>(in)[i];
    bh4 o = { __float2bfloat16(v.x), __float2bfloat16(v.y),
              __float2bfloat16(v.z), __float2bfloat16(v.w) };
    reinterpret_cast<bh4*>(out)[i] = o;
}

// transpose+convert: W[K][N] fp32 -> WT[N][K] bf16 (exact multiples of 32)
__global__ __launch_bounds__(256) void k_wT(const float* __restrict__ W,
        __hip_bfloat16* __restrict__ WT, int K, int N)
{
    __shared__ float t[32][33];
    int kb = blockIdx.x*32, nb = blockIdx.y*32;
    int tx = threadIdx.x & 31, ty = threadIdx.x >> 5;   // ty 0..7
    #pragma unroll
    for (int i = 0; i < 4; ++i)
        t[ty + i*8][tx] = W[(size_t)(kb + ty + i*8)*N + nb + tx];
    __syncthreads();
    #pragma unroll
    for (int i = 0; i < 4; ++i)
        WT[(size_t)(nb + ty + i*8)*K + kb + tx] = __float2bfloat16(t[tx][ty + i*8]);
}

// padded transpose+convert: W[K][N] fp32 -> WT[NP][KP] bf16, zero-filled
__global__ __launch_bounds__(256) void k_wTp(const float* __restrict__ W,
        __hip_bfloat16* __restrict__ WT, int K, int N, int KP)
{
    __shared__ float t[32][33];
    int kb = blockIdx.x*32, nb = blockIdx.y*32;
    int tx = threadIdx.x & 31, ty = threadIdx.x >> 5;
    #pragma unroll
    for (int i = 0; i < 4; ++i) {
        int k = kb + ty + i*8, n = nb + tx;
        t[ty + i*8][tx] = (k < K && n < N) ? W[(size_t)k*N + n] : 0.0f;
    }
    __syncthreads();
    #pragma unroll
    for (int i = 0; i < 4; ++i)
        WT[(size_t)(nb + ty + i*8)*KP + kb + tx] = __float2bfloat16(t[tx][ty + i*8]);
}

// ---------------- MFMA GEMM: 64x64 tile, depth-2 prefetch, counted vmcnt ----------------
template<bool ADD_VIS>
__global__ __launch_bounds__(256) void mfma_gemm(
        const __hip_bfloat16* __restrict__ A,   // [M][K]
        const __hip_bfloat16* __restrict__ WT,  // [N][K]
        const float* __restrict__ bias,         // [N]
        const float* __restrict__ vis,          // [8][1024]
        const int* __restrict__ bidx,           // [M]
        __hip_bfloat16* __restrict__ C,         // [M][N]
        int K)
{
    constexpr int N = 1024;
    __shared__ __align__(16) __hip_bfloat16 sA[3][4096];   // 3 x 8 KB
    __shared__ __align__(16) __hip_bfloat16 sB[3][4096];   // 3 x 8 KB
    int tid = threadIdx.x;
    int bm = blockIdx.x * 64, bn = blockIdx.y * 64;
    int wave = tid >> 6, lane = tid & 63;
    int wr = wave >> 1, wc = wave & 1;          // 2x2 wave grid, 32x32 each
    int l15 = lane & 15, l4 = lane >> 4;
    f32x4 acc[2][2] = {};

    const __hip_bfloat16* Ap = A  + (size_t)(bm + (tid & 63))*K + (tid >> 6)*8;
    const __hip_bfloat16* Bp = WT + (size_t)(bn + (tid & 63))*K + (tid >> 6)*8;

    int nsteps = K >> 6;
    auto STAGE = [&](int t, int b) {
        int ko = t << 6;
        char* la = (char*)&sA[b][0];
        char* lb = (char*)&sB[b][0];
        gld_lds16(Ap + ko,      la + tid*16);
        gld_lds16(Ap + ko + 32, la + (tid+256)*16);
        gld_lds16(Bp + ko,      lb + tid*16);
        gld_lds16(Bp + ko + 32, lb + (tid+256)*16);
    };
    STAGE(0, 0);
    if (nsteps > 1) STAGE(1, 1);

    for (int t = 0; t < nsteps; ++t) {
        if (t + 2 < nsteps) {
            STAGE(t + 2, (t + 2) % 3);
            asm volatile("s_waitcnt vmcnt(8)" ::: "memory");
        } else if (t + 1 < nsteps) {
            asm volatile("s_waitcnt vmcnt(4)" ::: "memory");
        } else {
            asm volatile("s_waitcnt vmcnt(0)" ::: "memory");
        }
        __builtin_amdgcn_s_barrier();   // tile t resident for all waves
        const __hip_bfloat16* sa = &sA[t % 3][0];
        const __hip_bfloat16* sb = &sB[t % 3][0];
        #pragma unroll
        for (int ks = 0; ks < 2; ++ks) {
            bf16x8 af[2], bfr[2];
            #pragma unroll
            for (int mi = 0; mi < 2; ++mi)
                af[mi] = *reinterpret_cast<const bf16x8*>(
                    &sa[(size_t)((ks*4 + l4)*64 + wr*32 + mi*16 + l15) * 8]);
            #pragma unroll
            for (int ni = 0; ni < 2; ++ni)
                bfr[ni] = *reinterpret_cast<const bf16x8*>(
                    &sb[(size_t)((ks*4 + l4)*64 + wc*32 + ni*16 + l15) * 8]);
            #pragma unroll
            for (int mi = 0; mi < 2; ++mi)
                #pragma unroll
                for (int ni = 0; ni < 2; ++ni)
                    acc[mi][ni] = __builtin_amdgcn_mfma_f32_16x16x32_bf16(
                        af[mi], bfr[ni], acc[mi][ni], 0, 0, 0);
        }
        __builtin_amdgcn_s_barrier();   // all waves done reading buf t%3
    }

    #pragma unroll
    for (int mi = 0; mi < 2; ++mi) {
        #pragma unroll
        for (int reg = 0; reg < 4; ++reg) {
            int row = bm + wr*32 + mi*16 + l4*4 + reg;
            const float* vrow = nullptr;
            if (ADD_VIS) vrow = vis + (size_t)bidx[row]*1024;
            #pragma unroll
            for (int ni = 0; ni < 2; ++ni) {
                int col = bn + wc*32 + ni*16 + l15;
                float v = acc[mi][ni][reg] + bias[col];
                if (ADD_VIS) v += vrow[col];
                v = fmaxf(v, 0.0f);
                C[(size_t)row*N + col] = __float2bfloat16(v);
            }
        }
    }
}

// final 1024 -> 6 (bf16 h)
__global__ __launch_bounds__(64) void k_final(const __hip_bfloat16* __restrict__ h,
        const float* __restrict__ w4, const float* __restrict__ b4, float* __restrict__ out)
{
    int t = blockIdx.x, lane = threadIdx.x;
    float acc[6] = {};
    for (int k = lane; k < DFF_; k += 64) {
        float hv = __bfloat162float(h[(size_t)t*DFF_ + k]);
        #pragma unroll
        for (int j = 0; j < 6; ++j) acc[j] = fmaf(hv, w4[k*6 + j], acc[j]);
    }
    #pragma unroll
    for (int j = 0; j < 6; ++j)
        #pragma unroll
        for (int s = 32; s > 0; s >>= 1) acc[j] += __shfl_down(acc[j], s);
    if (lane == 0) {
        #pragma unroll
        for (int j = 0; j < 6; ++j) out[(size_t)t*6 + j] = acc[j] + b4[j];
    }
}

extern "C" void kernel_launch(void* const* d_in, const int* in_sizes, int n_in,
                              void* d_out, int out_size, void* d_ws, size_t ws_size,
                              hipStream_t stream)
{
    const float* grd   = (const float*)d_in[0];
    const float* vfeat = (const float*)d_in[1];
    const int*   tbi   = (const int*)  d_in[2];
    const float* gB    = (const float*)d_in[3];
    const float* cemb  = (const float*)d_in[4];
    const float* w_in  = (const float*)d_in[5];
    const float* b_in  = (const float*)d_in[6];
    const float* w_out = (const float*)d_in[7];
    const float* b_out = (const float*)d_in[8];
    const float* ln1_s = (const float*)d_in[9];
    const float* ln1_b = (const float*)d_in[10];
    const float* w_ff1 = (const float*)d_in[11];
    const float* b_ff1 = (const float*)d_in[12];
    const float* w_ff2 = (const float*)d_in[13];
    const float* b_ff2 = (const float*)d_in[14];
    const float* ln2_s = (const float*)d_in[15];
    const float* ln2_b = (const float*)d_in[16];
    const float* w0    = (const float*)d_in[17];
    const float* b0    = (const float*)d_in[18];
    const float* w1    = (const float*)d_in[19];
    const float* b1    = (const float*)d_in[20];
    const float* w2    = (const float*)d_in[21];
    const float* b2    = (const float*)d_in[22];
    const float* w3    = (const float*)d_in[23];
    const float* b3    = (const float*)d_in[24];
    const float* w4    = (const float*)d_in[25];
    const float* b4    = (const float*)d_in[26];

    float* ws = (float*)d_ws;
    float* src    = ws;                       // 172032
    float* neg    = src    + 172032;          // 2048
    float* qkv    = neg    + 2048;            // 516096
    float* attn_o = qkv    + 516096;          // 172032
    float* vparts = attn_o + 172032;          // 168*8192 = 1376256
    float* vp2    = vparts + 1376256;         // 12*8192 = 98304
    float* visp   = vp2    + 98304;           // 8192
    float* ffpart = visp   + 8192;            // 1572864 (shared: attn partials / ff2 partials)
    float* fend   = ffpart + 1572864;
    __hip_bfloat16* grdb  = (__hip_bfloat16*)fend;       // 8388608
    __hip_bfloat16* w0t   = grdb  + 8388608;             // 4194304
    __hip_bfloat16* w1t   = w0t   + 4194304;             // 1048576
    __hip_bfloat16* w2t   = w1t   + 1048576;             // 1048576
    __hip_bfloat16* w3t   = w2t   + 1048576;             // 1048576
    __hip_bfloat16* hab   = w3t   + 1048576;             // 2097152
    __hip_bfloat16* hbb   = hab   + 2097152;             // 2097152
    __hip_bfloat16* srcb  = hbb   + 2097152;             // 262144
    __hip_bfloat16* wff1t = srcb  + 262144;              // 262144
    __hip_bfloat16* wff2t = wff1t + 262144;              // 196608
    __hip_bfloat16* ffh   = hab;  // alias: hab unused until head GEMMs

    // conversions (independent of encoder; issue first)
    k_f2b<<<(T_*LM_/4 + 255)/256, 256, 0, stream>>>(grd, grdb, T_*LM_/4);
    k_wT<<<dim3(LM_/32,  DFF_/32), 256, 0, stream>>>(w0 + (size_t)VISF_*DFF_, w0t, LM_,  DFF_);
    k_wT<<<dim3(DFF_/32, DFF_/32), 256, 0, stream>>>(w1, w1t, DFF_, DFF_);
    k_wT<<<dim3(DFF_/32, DFF_/32), 256, 0, stream>>>(w2, w2t, DFF_, DFF_);
    k_wT<<<dim3(DFF_/32, DFF_/32), 256, 0, stream>>>(w3, w3t, DFF_, DFF_);
    for (int l = 0; l < 2; ++l) {
        k_wTp<<<dim3(128/32, 1024/32), 256, 0, stream>>>(
            w_ff1 + (size_t)l*D_*DFF_, wff1t + (size_t)l*1024*128, D_, DFF_, 128);
        k_wTp<<<dim3(1024/32, 96/32),  256, 0, stream>>>(
            w_ff2 + (size_t)l*DFF_*D_, wff2t + (size_t)l*96*1024, DFF_, D_, 1024);
    }

    k_build_src<<<8, 256, 0, stream>>>(vfeat, gB, cemb, src, neg);

    for (int lay = 0; lay < 2; ++lay) {
        k_qkv8      <<<BL_/8, 256, 0, stream>>>(src, w_in, b_in, qkv, lay);
        k_attn_part <<<dim3(B_*H_, AKS), 256, 0, stream>>>(qkv, neg, ffpart);
        k_attn_merge<<<dim3(B_*H_, 4), 64, 0, stream>>>(ffpart, attn_o);
        k_oproj_ln  <<<BL_, 128, 0, stream>>>(attn_o, w_out, b_out, ln1_s, ln1_b, src, srcb, lay);
        mfma_gemm<false><<<dim3(32, 16), 256, 0, stream>>>(
            srcb, wff1t + (size_t)lay*1024*128, b_ff1 + lay*DFF_,
            nullptr, nullptr, ffh, 128);
        k_ff2_mfma<<<dim3(32, 8), 256, 0, stream>>>(
            ffh, wff2t + (size_t)lay*96*1024, ffpart);
        k_ff2ln_red<<<BL_, 128, 0, stream>>>(ffpart, b_ff2, ln2_s, ln2_b, src, lay);
    }

    k_vis_gemm<<<dim3(8, VKS), 256, 0, stream>>>(src, w0, vparts);
    k_vis_red1<<<dim3(32, 12), 256, 0, stream>>>(vparts, vp2);
    k_vis_red2<<<32, 256, 0, stream>>>(vp2, visp);

    dim3 mg(T_/64, DFF_/64);   // (32, 16) = 512 blocks, 2 blocks/CU
    mfma_gemm<true ><<<mg, 256, 0, stream>>>(grdb, w0t, b0, visp, tbi, hab, LM_);
    mfma_gemm<false><<<mg, 256, 0, stream>>>(hab,  w1t, b1, nullptr, nullptr, hbb, DFF_);
    mfma_gemm<false><<<mg, 256, 0, stream>>>(hbb,  w2t, b2, nullptr, nullptr, hab, DFF_);
    mfma_gemm<false><<<mg, 256, 0, stream>>>(hab,  w3t, b3, nullptr, nullptr, hbb, DFF_);

    k_final<<<T_, 64, 0, stream>>>(hbb, w4, b4, (float*)d_out);
}